// Round 13
// baseline (378.886 us; speedup 1.0000x reference)
//
#include <hip/hip_runtime.h>
#include <math.h>

#define SEQ 12
#define NBATCH 16384   // BC*NODES
#define FEAT 32
#define HID 64
#define NSPLIT 4       // KV-split factor for GAT fast path

// ---- fallback packed-weight layout (floats, round-2 format) ----
#define WP_IH0 0
#define WP_HH0 6144
#define WP_IH1 18432
#define WP_HH1 30720
#define WP_TOTAL 43008

typedef __attribute__((ext_vector_type(8))) short bf16x8;   // 8 bf16 = 4 VGPR
typedef __attribute__((ext_vector_type(4))) float f32x4;

#define MFMA_B16(A,B,C) __builtin_amdgcn_mfma_f32_16x16x32_bf16((A),(B),(C),0,0,0)

union B8u { unsigned short s[8]; bf16x8 v; };

__device__ __forceinline__ float sigf(float x) { return 1.0f / (1.0f + __expf(-x)); }
__device__ __forceinline__ float tanh_fast(float x) { return 2.0f / (1.0f + __expf(-2.0f * x)) - 1.0f; }

__device__ __forceinline__ unsigned int packsplit(float v) {
  unsigned int u  = __float_as_uint(v);
  unsigned int hi = u & 0xFFFF0000u;
  unsigned int lo = __float_as_uint(v - __uint_as_float(hi)) >> 16;
  return hi | lo;
}

__device__ __forceinline__ void unpack8(const unsigned int* p, bf16x8& H, bf16x8& L) {
  uint4 u0 = *(const uint4*)p;
  uint4 u1 = *(const uint4*)(p + 4);
  unsigned int uu[8] = {u0.x, u0.y, u0.z, u0.w, u1.x, u1.y, u1.z, u1.w};
  B8u hh, ll;
  #pragma unroll
  for (int i = 0; i < 8; i++) {
    hh.s[i] = (unsigned short)(uu[i] >> 16);
    ll.s[i] = (unsigned short)(uu[i] & 0xFFFFu);
  }
  H = hh.v; L = ll.v;
}

__device__ __forceinline__ void split8(const float* fa, bf16x8& H, bf16x8& L) {
  B8u hh, ll;
  #pragma unroll
  for (int i = 0; i < 8; i++) {
    unsigned int u  = __float_as_uint(fa[i]);
    unsigned int hi = u & 0xFFFF0000u;
    hh.s[i] = (unsigned short)(hi >> 16);
    ll.s[i] = (unsigned short)(__float_as_uint(fa[i] - __uint_as_float(hi)) >> 16);
  }
  H = hh.v; L = ll.v;
}

#define DOT4(acc, A_, B_)                                   \
  acc = fmaf((A_).x, (B_).x, acc);                          \
  acc = fmaf((A_).y, (B_).y, acc);                          \
  acc = fmaf((A_).z, (B_).z, acc);                          \
  acc = fmaf((A_).w, (B_).w, acc);

// ===========================================================================
// Weight pre-pack into MFMA B-fragments (hi/lo planes). Verified rounds 4-10.
// ===========================================================================
__global__ void prep_frag_kernel(const float* __restrict__ w_ih0, const float* __restrict__ w_hh0,
                                 const float* __restrict__ w_ih1, const float* __restrict__ w_hh1,
                                 unsigned short* __restrict__ wf)
{
  int i = blockIdx.x * blockDim.x + threadIdx.x;   // 0..43007
  if (i >= 43008) return;
  const float* src; int K, rel, baseS;
  if (i < 6144)       { src = w_ih0; K = 32; rel = i;         baseS = 0; }
  else if (i < 18432) { src = w_hh0; K = 64; rel = i - 6144;  baseS = 12288; }
  else if (i < 30720) { src = w_ih1; K = 64; rel = i - 18432; baseS = 36864; }
  else                { src = w_hh1; K = 64; rel = i - 30720; baseS = 61440; }
  int nks = K / 32;
  int fp   = rel >> 9;
  int lane = (rel >> 3) & 63;
  int e    = rel & 7;
  int ct = fp / nks, ks = fp % nks;
  int g = ct * 16 + (lane & 15);
  int k = ks * 32 + (lane >> 4) * 8 + e;
  float v = src[g * K + k];
  unsigned int u = __float_as_uint(v);
  unsigned short hi = (unsigned short)(u >> 16);
  float hif = __uint_as_float(u & 0xFFFF0000u);
  unsigned short lo = (unsigned short)(__float_as_uint(v - hif) >> 16);
  int out = baseS + fp * 1024 + lane * 8 + e;
  wf[out]       = hi;
  wf[out + 512] = lo;
}

// mask [1024][1024] int -> bitmask [1024][32] u32 (128KB, L1/L2-hot)
__global__ void mask_pack(const int* __restrict__ mask, unsigned int* __restrict__ mbits)
{
  int i = blockIdx.x * blockDim.x + threadIdx.x;   // 0..32767
  if (i >= 32768) return;
  int r = i >> 5, wd = i & 31;
  const int* mp = mask + (size_t)r * 1024 + wd * 32;
  unsigned int b = 0;
  #pragma unroll
  for (int k = 0; k < 32; k++) b |= (mp[k] != 0 ? 1u : 0u) << k;
  mbits[i] = b;
}

// ===========================================================================
// FUSED 2-layer MFMA GRU v2:
//  - h-state in SEPARATE hi/lo bf16 LDS planes (stride 72 ushort = 144B:
//    16B-aligned b128 reads, <=2-way banks) -> zero unpack VALU ops
//  - __launch_bounds__(256,4): 4 blocks/CU (VGPR fit 128 naturally)
//  - ONE barrier per t (double-buffer + block rendezvous covers all hazards)
// ===========================================================================
#define HSTR 72
__global__ __launch_bounds__(256, 4) void gru_fused(
    const float* __restrict__ x, const unsigned short* __restrict__ wf,
    const float* __restrict__ b_ih0, const float* __restrict__ b_hh0,
    const float* __restrict__ b_ih1, const float* __restrict__ b_hh1,
    unsigned int* __restrict__ zpk0, unsigned int* __restrict__ zpk1)
{
  __shared__ unsigned short h0h[2][16 * HSTR], h0o[2][16 * HSTR];
  __shared__ unsigned short h1h[2][16 * HSTR], h1o[2][16 * HSTR];
  const int tid = threadIdx.x;
  const int w = tid >> 6, l = tid & 63, lr = l & 15, lg = l >> 4;
  const int s0 = blockIdx.x * 16;
  const int j = w * 16 + lr;

  // ---- B-fragments -> VGPRs (identical addresses across blocks: L2-hot) ----
  bf16x8 Wih0[3][2], Whh0[3][2][2], Wih1[3][2][2], Whh1[3][2][2];
  #pragma unroll
  for (int g = 0; g < 3; g++) {
    const int ct = w + g * 4;
    Wih0[g][0] = *(const bf16x8*)&wf[ct * 1024 + l * 8];
    Wih0[g][1] = *(const bf16x8*)&wf[ct * 1024 + 512 + l * 8];
    #pragma unroll
    for (int ks = 0; ks < 2; ks++) {
      Whh0[g][ks][0] = *(const bf16x8*)&wf[12288 + (ct * 2 + ks) * 1024 + l * 8];
      Whh0[g][ks][1] = *(const bf16x8*)&wf[12288 + (ct * 2 + ks) * 1024 + 512 + l * 8];
      Wih1[g][ks][0] = *(const bf16x8*)&wf[36864 + (ct * 2 + ks) * 1024 + l * 8];
      Wih1[g][ks][1] = *(const bf16x8*)&wf[36864 + (ct * 2 + ks) * 1024 + 512 + l * 8];
      Whh1[g][ks][0] = *(const bf16x8*)&wf[61440 + (ct * 2 + ks) * 1024 + l * 8];
      Whh1[g][ks][1] = *(const bf16x8*)&wf[61440 + (ct * 2 + ks) * 1024 + 512 + l * 8];
    }
  }

  const float br0  = b_ih0[j]      + b_hh0[j];
  const float bz0  = b_ih0[64 + j] + b_hh0[64 + j];
  const float bni0 = b_ih0[128 + j];
  const float bnh0 = b_hh0[128 + j];
  const float br1  = b_ih1[j]      + b_hh1[j];
  const float bz1  = b_ih1[64 + j] + b_hh1[64 + j];
  const float bni1 = b_ih1[128 + j];
  const float bnh1 = b_hh1[128 + j];

  for (int i = tid; i < 16 * HSTR; i += 256) {
    h0h[0][i] = 0; h0o[0][i] = 0; h1h[0][i] = 0; h1o[0][i] = 0;
  }
  float hD0[4] = {0.f, 0.f, 0.f, 0.f};
  float hD1[4] = {0.f, 0.f, 0.f, 0.f};
  __syncthreads();

  float4 xc0 = *(const float4*)(x + ((size_t)s0 + lr) * FEAT + lg * 8);
  float4 xc1 = *(const float4*)(x + ((size_t)s0 + lr) * FEAT + lg * 8 + 4);

  int pb = 0;
  #pragma unroll 1
  for (int t = 0; t < SEQ; t++) {
    const int cb = pb ^ 1;
    float4 xn0, xn1;
    if (t < SEQ - 1) {
      const float* xp = x + ((size_t)(t + 1) * NBATCH + s0 + lr) * FEAT + lg * 8;
      xn0 = *(const float4*)xp;
      xn1 = *(const float4*)(xp + 4);
    }

    // ================= layer 0 =================
    f32x4 aR, aZ, aNI, aNH;
    #pragma unroll
    for (int e = 0; e < 4; e++) { aR[e] = br0; aZ[e] = bz0; aNI[e] = bni0; aNH[e] = bnh0; }
    {
      float fa[8] = {xc0.x, xc0.y, xc0.z, xc0.w, xc1.x, xc1.y, xc1.z, xc1.w};
      bf16x8 Ah, Al;
      split8(fa, Ah, Al);
      aR  = MFMA_B16(Ah, Wih0[0][0], aR);  aR  = MFMA_B16(Al, Wih0[0][0], aR);  aR  = MFMA_B16(Ah, Wih0[0][1], aR);
      aZ  = MFMA_B16(Ah, Wih0[1][0], aZ);  aZ  = MFMA_B16(Al, Wih0[1][0], aZ);  aZ  = MFMA_B16(Ah, Wih0[1][1], aZ);
      aNI = MFMA_B16(Ah, Wih0[2][0], aNI); aNI = MFMA_B16(Al, Wih0[2][0], aNI); aNI = MFMA_B16(Ah, Wih0[2][1], aNI);
    }
    #pragma unroll
    for (int ks = 0; ks < 2; ks++) {
      bf16x8 Ah = *(const bf16x8*)&h0h[pb][lr * HSTR + ks * 32 + lg * 8];
      bf16x8 Al = *(const bf16x8*)&h0o[pb][lr * HSTR + ks * 32 + lg * 8];
      aR  = MFMA_B16(Ah, Whh0[0][ks][0], aR);  aR  = MFMA_B16(Al, Whh0[0][ks][0], aR);  aR  = MFMA_B16(Ah, Whh0[0][ks][1], aR);
      aZ  = MFMA_B16(Ah, Whh0[1][ks][0], aZ);  aZ  = MFMA_B16(Al, Whh0[1][ks][0], aZ);  aZ  = MFMA_B16(Ah, Whh0[1][ks][1], aZ);
      aNH = MFMA_B16(Ah, Whh0[2][ks][0], aNH); aNH = MFMA_B16(Al, Whh0[2][ks][0], aNH); aNH = MFMA_B16(Ah, Whh0[2][ks][1], aNH);
    }
    #pragma unroll
    for (int e = 0; e < 4; e++) {
      float rg = sigf(aR[e]);
      float zg = sigf(aZ[e]);
      float n  = tanh_fast(fmaf(rg, aNH[e], aNI[e]));
      float hn = fmaf(zg, hD0[e] - n, n);
      hD0[e] = hn;
      unsigned int pk = packsplit(hn);
      int idx = (lg * 4 + e) * HSTR + j;
      h0h[cb][idx] = (unsigned short)(pk >> 16);
      h0o[cb][idx] = (unsigned short)(pk & 0xFFFFu);
    }
    __syncthreads();   // h0_new visible; also orders all cross-t hazards

    // ================= layer 1 =================
    #pragma unroll
    for (int e = 0; e < 4; e++) { aR[e] = br1; aZ[e] = bz1; aNI[e] = bni1; aNH[e] = bnh1; }
    #pragma unroll
    for (int ks = 0; ks < 2; ks++) {
      bf16x8 Ah = *(const bf16x8*)&h0h[cb][lr * HSTR + ks * 32 + lg * 8];
      bf16x8 Al = *(const bf16x8*)&h0o[cb][lr * HSTR + ks * 32 + lg * 8];
      aR  = MFMA_B16(Ah, Wih1[0][ks][0], aR);  aR  = MFMA_B16(Al, Wih1[0][ks][0], aR);  aR  = MFMA_B16(Ah, Wih1[0][ks][1], aR);
      aZ  = MFMA_B16(Ah, Wih1[1][ks][0], aZ);  aZ  = MFMA_B16(Al, Wih1[1][ks][0], aZ);  aZ  = MFMA_B16(Ah, Wih1[1][ks][1], aZ);
      aNI = MFMA_B16(Ah, Wih1[2][ks][0], aNI); aNI = MFMA_B16(Al, Wih1[2][ks][0], aNI); aNI = MFMA_B16(Ah, Wih1[2][ks][1], aNI);
    }
    #pragma unroll
    for (int ks = 0; ks < 2; ks++) {
      bf16x8 Ah = *(const bf16x8*)&h1h[pb][lr * HSTR + ks * 32 + lg * 8];
      bf16x8 Al = *(const bf16x8*)&h1o[pb][lr * HSTR + ks * 32 + lg * 8];
      aR  = MFMA_B16(Ah, Whh1[0][ks][0], aR);  aR  = MFMA_B16(Al, Whh1[0][ks][0], aR);  aR  = MFMA_B16(Ah, Whh1[0][ks][1], aR);
      aZ  = MFMA_B16(Ah, Whh1[1][ks][0], aZ);  aZ  = MFMA_B16(Al, Whh1[1][ks][0], aZ);  aZ  = MFMA_B16(Ah, Whh1[1][ks][1], aZ);
      aNH = MFMA_B16(Ah, Whh1[2][ks][0], aNH); aNH = MFMA_B16(Al, Whh1[2][ks][0], aNH); aNH = MFMA_B16(Ah, Whh1[2][ks][1], aNH);
    }
    #pragma unroll
    for (int e = 0; e < 4; e++) {
      float rg = sigf(aR[e]);
      float zg = sigf(aZ[e]);
      float n  = tanh_fast(fmaf(rg, aNH[e], aNI[e]));
      float hn = fmaf(zg, hD1[e] - n, n);
      hD1[e] = hn;
      unsigned int pk = packsplit(hn);
      int idx = (lg * 4 + e) * HSTR + j;
      h1h[cb][idx] = (unsigned short)(pk >> 16);
      h1o[cb][idx] = (unsigned short)(pk & 0xFFFFu);
    }
    // no end-of-t barrier: next t's mid-barrier orders all remaining hazards
    xc0 = xn0; xc1 = xn1;
    pb = cb;
  }

  #pragma unroll
  for (int e = 0; e < 4; e++) {
    int sl = lg * 4 + e;
    zpk0[(size_t)(s0 + sl) * 64 + j] = packsplit(hD0[e]);
    zpk1[(size_t)(s0 + sl) * 64 + j] = packsplit(hD1[e]);
  }
}

// ===========================================================================
// FALLBACK (small ws): round-2 LDS-weight GRU, writes PACKED z
// ===========================================================================
__global__ void prep_kernel(const float* __restrict__ w_ih0, const float* __restrict__ w_hh0,
                            const float* __restrict__ w_ih1, const float* __restrict__ w_hh1,
                            float* __restrict__ wp)
{
  for (int i = blockIdx.x * blockDim.x + threadIdx.x; i < WP_TOTAL; i += gridDim.x * blockDim.x) {
    const float* src;
    int K, rel;
    if (i < WP_HH0)      { src = w_ih0; K = 32; rel = i; }
    else if (i < WP_IH1) { src = w_hh0; K = 64; rel = i - WP_HH0; }
    else if (i < WP_HH1) { src = w_ih1; K = 64; rel = i - WP_IH1; }
    else                 { src = w_hh1; K = 64; rel = i - WP_HH1; }
    int kr = rel & 3;
    int jj = (rel >> 2) & 63;
    int rest = rel >> 8;
    int g = rest % 3;
    int k4 = rest / 3;
    wp[i] = src[(g * 64 + jj) * K + k4 * 4 + kr];
  }
}

__global__ __launch_bounds__(256, 1) void gru_fallback(
    const float* __restrict__ x, const float* __restrict__ wpack,
    const float* __restrict__ b_ih0, const float* __restrict__ b_hh0,
    const float* __restrict__ b_ih1, const float* __restrict__ b_hh1,
    unsigned int* __restrict__ zout)
{
  __shared__ float wlds[36864];
  __shared__ float h0s[16][64];
  __shared__ float h1s[16][64];
  const int tid = threadIdx.x;
  {
    const float4* src = (const float4*)(wpack + WP_HH0);
    float4* dst = (float4*)wlds;
    #pragma unroll 4
    for (int i = tid; i < 9216; i += 256) dst[i] = src[i];
  }
  const int j  = tid & 63;
  const int sg = __builtin_amdgcn_readfirstlane(tid >> 6);
  const float br0  = b_ih0[j]      + b_hh0[j];
  const float bz0  = b_ih0[64 + j] + b_hh0[64 + j];
  const float bni0 = b_ih0[128 + j];
  const float bnh0 = b_hh0[128 + j];
  const float br1  = b_ih1[j]      + b_hh1[j];
  const float bz1  = b_ih1[64 + j] + b_hh1[64 + j];
  const float bni1 = b_ih1[128 + j];
  const float bnh1 = b_hh1[128 + j];
  const int s0 = blockIdx.x * 16;
  float h0r[4] = {0.f, 0.f, 0.f, 0.f};
  float h1r[4] = {0.f, 0.f, 0.f, 0.f};
  #pragma unroll
  for (int ss = 0; ss < 4; ss++) { h0s[sg * 4 + ss][j] = 0.f; h1s[sg * 4 + ss][j] = 0.f; }
  __syncthreads();
  const float4* wih0g = (const float4*)(wpack + WP_IH0);
  const float4* whh0l = (const float4*)(wlds);
  const float4* wih1l = (const float4*)(wlds + 12288);
  const float4* whh1l = (const float4*)(wlds + 24576);
  for (int t = 0; t < SEQ; t++) {
    float ar[4], az[4], ani[4], anh[4];
    #pragma unroll
    for (int ss = 0; ss < 4; ss++) { ar[ss] = br0; az[ss] = bz0; ani[ss] = bni0; anh[ss] = bnh0; }
    const float4* xr0 = (const float4*)(x + ((size_t)t * NBATCH + (s0 + sg * 4 + 0)) * FEAT);
    const float4* xr1 = (const float4*)(x + ((size_t)t * NBATCH + (s0 + sg * 4 + 1)) * FEAT);
    const float4* xr2 = (const float4*)(x + ((size_t)t * NBATCH + (s0 + sg * 4 + 2)) * FEAT);
    const float4* xr3 = (const float4*)(x + ((size_t)t * NBATCH + (s0 + sg * 4 + 3)) * FEAT);
    #pragma unroll
    for (int k4 = 0; k4 < 8; k4++) {
      float4 wr = wih0g[(k4 * 3 + 0) * 64 + j];
      float4 wz = wih0g[(k4 * 3 + 1) * 64 + j];
      float4 wn = wih0g[(k4 * 3 + 2) * 64 + j];
      float4 xv[4] = {xr0[k4], xr1[k4], xr2[k4], xr3[k4]};
      #pragma unroll
      for (int ss = 0; ss < 4; ss++) {
        DOT4(ar[ss],  wr, xv[ss]);
        DOT4(az[ss],  wz, xv[ss]);
        DOT4(ani[ss], wn, xv[ss]);
      }
    }
    #pragma unroll
    for (int k4 = 0; k4 < 16; k4++) {
      float4 wr = whh0l[(k4 * 3 + 0) * 64 + j];
      float4 wz = whh0l[(k4 * 3 + 1) * 64 + j];
      float4 wn = whh0l[(k4 * 3 + 2) * 64 + j];
      #pragma unroll
      for (int ss = 0; ss < 4; ss++) {
        float4 hv = *(const float4*)&h0s[sg * 4 + ss][k4 * 4];
        DOT4(ar[ss],  wr, hv);
        DOT4(az[ss],  wz, hv);
        DOT4(anh[ss], wn, hv);
      }
    }
    float h0n[4];
    #pragma unroll
    for (int ss = 0; ss < 4; ss++) {
      float rg = sigf(ar[ss]);
      float zg = sigf(az[ss]);
      float ng = tanh_fast(fmaf(rg, anh[ss], ani[ss]));
      h0n[ss] = fmaf(zg, h0r[ss] - ng, ng);
    }
    __syncthreads();
    #pragma unroll
    for (int ss = 0; ss < 4; ss++) { h0s[sg * 4 + ss][j] = h0n[ss]; h0r[ss] = h0n[ss]; }
    __syncthreads();
    #pragma unroll
    for (int ss = 0; ss < 4; ss++) { ar[ss] = br1; az[ss] = bz1; ani[ss] = bni1; anh[ss] = bnh1; }
    #pragma unroll
    for (int k4 = 0; k4 < 16; k4++) {
      float4 wr = wih1l[(k4 * 3 + 0) * 64 + j];
      float4 wz = wih1l[(k4 * 3 + 1) * 64 + j];
      float4 wn = wih1l[(k4 * 3 + 2) * 64 + j];
      #pragma unroll
      for (int ss = 0; ss < 4; ss++) {
        float4 hv = *(const float4*)&h0s[sg * 4 + ss][k4 * 4];
        DOT4(ar[ss],  wr, hv);
        DOT4(az[ss],  wz, hv);
        DOT4(ani[ss], wn, hv);
      }
    }
    #pragma unroll
    for (int k4 = 0; k4 < 16; k4++) {
      float4 wr = whh1l[(k4 * 3 + 0) * 64 + j];
      float4 wz = whh1l[(k4 * 3 + 1) * 64 + j];
      float4 wn = whh1l[(k4 * 3 + 2) * 64 + j];
      #pragma unroll
      for (int ss = 0; ss < 4; ss++) {
        float4 hv = *(const float4*)&h1s[sg * 4 + ss][k4 * 4];
        DOT4(ar[ss],  wr, hv);
        DOT4(az[ss],  wz, hv);
        DOT4(anh[ss], wn, hv);
      }
    }
    float h1n[4];
    #pragma unroll
    for (int ss = 0; ss < 4; ss++) {
      float rg = sigf(ar[ss]);
      float zg = sigf(az[ss]);
      float ng = tanh_fast(fmaf(rg, anh[ss], ani[ss]));
      h1n[ss] = fmaf(zg, h1r[ss] - ng, ng);
    }
    __syncthreads();
    #pragma unroll
    for (int ss = 0; ss < 4; ss++) { h1s[sg * 4 + ss][j] = h1n[ss]; h1r[ss] = h1n[ss]; }
    __syncthreads();
  }
  #pragma unroll
  for (int ss = 0; ss < 4; ss++) {
    int s = s0 + sg * 4 + ss;
    zout[(size_t)s * 64 + j]            = packsplit(h0r[ss]);
    zout[(size_t)(NBATCH + s) * 64 + j] = packsplit(h1r[ss]);
  }
}

// ===========================================================================
// MFMA GAT v4 (verified round 10): KV-split flash attention, fixed-max softmax.
// ===========================================================================
__global__ __launch_bounds__(256, 4) void gat_mfma4(
    const unsigned int* __restrict__ zpk, const unsigned int* __restrict__ mbits,
    float* __restrict__ partO, float* __restrict__ partD,
    float* __restrict__ out, int nsplit)
{
  __shared__ unsigned int VT[64 * 68];   // packed hi|lo, [d][s] layout
  __shared__ float        PS[64 * 68];   // P fp32, wave-private rows
  const int tid = threadIdx.x;
  const int w = tid >> 6, l = tid & 63, lr = l & 15, lg = l >> 4;
  const int blk  = blockIdx.x;
  const int lbrt = blk / nsplit;
  const int half = blk - lbrt * nsplit;
  const int rt = lbrt & 15;
  const int lb = lbrt >> 4;
  const int tiles = 16 / nsplit;
  const int mt0 = half * tiles;
  const unsigned int* zb = zpk + (size_t)lb * 65536;
  const int n0 = rt * 64;

  bf16x8 Qh[2], Ql[2];
  #pragma unroll
  for (int ks = 0; ks < 2; ks++)
    unpack8(&zb[(size_t)(n0 + w * 16 + lr) * 64 + ks * 32 + lg * 8], Qh[ks], Ql[ks]);

  f32x4 O[4];
  float D[4] = {0.f, 0.f, 0.f, 0.f};
  #pragma unroll
  for (int ct = 0; ct < 4; ct++)
    #pragma unroll
    for (int e = 0; e < 4; e++) O[ct][e] = 0.f;

  #pragma unroll 1
  for (int mt = mt0; mt < mt0 + tiles; ++mt) {
    __syncthreads();
    {
      unsigned int tmp[16];
      #pragma unroll
      for (int r = 0; r < 16; r++)
        tmp[r] = zb[(size_t)(mt * 64 + w * 16 + r) * 64 + l];
      #pragma unroll
      for (int q = 0; q < 4; q++)
        *(uint4*)&VT[l * 68 + w * 16 + q * 4] =
            make_uint4(tmp[q * 4], tmp[q * 4 + 1], tmp[q * 4 + 2], tmp[q * 4 + 3]);
    }
    __syncthreads();

    // S = Q.K^T (3-term split, full precision through exp)
    f32x4 S[4];
    #pragma unroll
    for (int ct = 0; ct < 4; ct++)
      #pragma unroll
      for (int e = 0; e < 4; e++) S[ct][e] = 0.f;
    #pragma unroll
    for (int ks = 0; ks < 2; ks++) {
      #pragma unroll
      for (int ct = 0; ct < 4; ct++) {
        bf16x8 Kh, Kl;
        unpack8(&zb[(size_t)(mt * 64 + ct * 16 + lr) * 64 + ks * 32 + lg * 8], Kh, Kl);
        S[ct] = MFMA_B16(Qh[ks], Kh, S[ct]);
        S[ct] = MFMA_B16(Ql[ks], Kh, S[ct]);
        S[ct] = MFMA_B16(Qh[ks], Kl, S[ct]);
      }
    }

    // fixed-max masked softmax: P = exp(leaky(S)-64), masked/zero -> 0
    #pragma unroll
    for (int e = 0; e < 4; e++) {
      const int row = n0 + w * 16 + lg * 4 + e;
      const uint2 mw = *(const uint2*)&mbits[(size_t)row * 32 + mt * 2];
      const unsigned int sel[4] = {mw.x >> lr, mw.x >> (16 + lr), mw.y >> lr, mw.y >> (16 + lr)};
      float ds = 0.f;
      #pragma unroll
      for (int ct = 0; ct < 4; ct++) {
        float v = S[ct][e];
        float lrv = v > 0.f ? v : 0.1f * v;
        float p = ((sel[ct] & 1u) && lrv != 0.0f) ? __expf(lrv - 64.0f) : 0.0f;
        ds += p;
        PS[(w * 16 + lg * 4 + e) * 68 + ct * 16 + lr] = p;
      }
      D[e] += ds;
    }

    // O += P.V  (P bf16-RNE single term; V full hi+lo)
    #pragma unroll
    for (int ks = 0; ks < 2; ks++) {
      const float* pp = &PS[(w * 16 + lr) * 68 + ks * 32 + lg * 8];
      float4 p0 = *(const float4*)pp;
      float4 p1 = *(const float4*)(pp + 4);
      float fa[8] = {p0.x, p0.y, p0.z, p0.w, p1.x, p1.y, p1.z, p1.w};
      B8u H;
      #pragma unroll
      for (int i = 0; i < 8; i++)
        H.s[i] = (unsigned short)((__float_as_uint(fa[i]) + 0x8000u) >> 16);
      bf16x8 Ph = H.v;
      #pragma unroll
      for (int ct = 0; ct < 4; ct++) {
        bf16x8 Vh, Vl;
        unpack8(&VT[(ct * 16 + lr) * 68 + ks * 32 + lg * 8], Vh, Vl);
        O[ct] = MFMA_B16(Ph, Vh, O[ct]);
        O[ct] = MFMA_B16(Ph, Vl, O[ct]);
      }
    }
  }

  // reduce D across the 16 lanes of each row group (once, not per-mt)
  #pragma unroll
  for (int e = 0; e < 4; e++) {
    #pragma unroll
    for (int sw = 1; sw < 16; sw <<= 1) D[e] += __shfl_xor(D[e], sw, 16);
  }

  if (nsplit == 1) {
    #pragma unroll
    for (int e = 0; e < 4; e++) {
      float inv = 1.0f / D[e];
      size_t rowo = ((size_t)lb * 1024 + n0 + w * 16 + lg * 4 + e) * 64;
      #pragma unroll
      for (int ct = 0; ct < 4; ct++)
        out[rowo + ct * 16 + lr] = O[ct][e] * inv;
    }
  } else {
    float* po = partO + (size_t)blk * 4096;
    #pragma unroll
    for (int e = 0; e < 4; e++) {
      int row = w * 16 + lg * 4 + e;
      #pragma unroll
      for (int ct = 0; ct < 4; ct++)
        po[row * 64 + ct * 16 + lr] = O[ct][e];
      if (lr == 0) partD[(size_t)blk * 64 + row] = D[e];
    }
  }
}

// merge: out = sum_i O_i / sum_i D_i  (fixed max -> plain sums, no exp)
__global__ __launch_bounds__(256) void gat_combine(
    const float* __restrict__ partO, const float* __restrict__ partD,
    float* __restrict__ out, int nsplit)
{
  const int lbrt = blockIdx.x;             // 0..511
  const int q  = threadIdx.x >> 2;         // 0..63
  const int dc = (threadIdx.x & 3) * 16;   // 0,16,32,48
  float dt = 0.f;
  for (int i = 0; i < nsplit; i++) dt += partD[(size_t)(lbrt * nsplit + i) * 64 + q];
  float inv = 1.0f / dt;
  float* op = out + ((size_t)lbrt * 64 + q) * 64 + dc;
  #pragma unroll
  for (int v = 0; v < 4; v++) {
    float4 acc = make_float4(0.f, 0.f, 0.f, 0.f);
    for (int i = 0; i < nsplit; i++) {
      const float4 o = *(const float4*)(partO + (size_t)(lbrt * nsplit + i) * 4096 + q * 64 + dc + v * 4);
      acc.x += o.x; acc.y += o.y; acc.z += o.z; acc.w += o.w;
    }
    *(float4*)(op + v * 4) = make_float4(acc.x * inv, acc.y * inv, acc.z * inv, acc.w * inv);
  }
}

extern "C" void kernel_launch(void* const* d_in, const int* in_sizes, int n_in,
                              void* d_out, int out_size, void* d_ws, size_t ws_size,
                              hipStream_t stream) {
  const float* h     = (const float*)d_in[0];
  const int*   mask  = (const int*)d_in[1];
  const float* w_ih0 = (const float*)d_in[2];
  const float* w_hh0 = (const float*)d_in[3];
  const float* b_ih0 = (const float*)d_in[4];
  const float* b_hh0 = (const float*)d_in[5];
  const float* w_ih1 = (const float*)d_in[6];
  const float* w_hh1 = (const float*)d_in[7];
  const float* b_ih1 = (const float*)d_in[8];
  const float* b_hh1 = (const float*)d_in[9];
  float* out = (float*)d_out;

  char* wsb = (char*)d_ws;
  unsigned int* zpk = (unsigned int*)wsb;                     // [2][16384][64] packed u32
  const size_t Z_BYTES  = (size_t)2 * NBATCH * 64 * 4;        // 8388608
  const size_t PART_OFF = Z_BYTES + 176128;                   // past 172KB frag weights
  const size_t PO_BYTES = (size_t)512 * NSPLIT * 4096 * 4;    // 33.6MB
  const size_t PD_BYTES = (size_t)512 * NSPLIT * 64 * 4;      // 512KB
  const size_t MB_OFF   = PART_OFF + PO_BYTES + PD_BYTES;
  const size_t NEED_FAST = MB_OFF + 131072;

  if (ws_size >= NEED_FAST) {
    unsigned short* wfrag = (unsigned short*)(wsb + Z_BYTES);
    float* partO  = (float*)(wsb + PART_OFF);
    float* partD  = (float*)(wsb + PART_OFF + PO_BYTES);
    unsigned int* mbits = (unsigned int*)(wsb + MB_OFF);
    prep_frag_kernel<<<168, 256, 0, stream>>>(w_ih0, w_hh0, w_ih1, w_hh1, wfrag);
    mask_pack<<<128, 256, 0, stream>>>(mask, mbits);
    gru_fused<<<1024, 256, 0, stream>>>(h, wfrag, b_ih0, b_hh0, b_ih1, b_hh1,
                                        zpk, zpk + (size_t)NBATCH * 64);
    gat_mfma4<<<512 * NSPLIT, 256, 0, stream>>>(zpk, mbits, partO, partD, out, NSPLIT);
    gat_combine<<<512, 256, 0, stream>>>(partO, partD, out, NSPLIT);
  } else {
    float* wpack = (float*)(wsb + Z_BYTES);
    unsigned int* mbits = (unsigned int*)(wsb + Z_BYTES + 172032);
    prep_kernel<<<24, 256, 0, stream>>>(w_ih0, w_hh0, w_ih1, w_hh1, wpack);
    mask_pack<<<128, 256, 0, stream>>>(mask, mbits);
    gru_fallback<<<1024, 256, 0, stream>>>(h, wpack, b_ih0, b_hh0, b_ih1, b_hh1, zpk);
    gat_mfma4<<<512, 256, 0, stream>>>(zpk, mbits, nullptr, nullptr, out, 1);
  }
}

// Round 14
// 181.357 us; speedup vs baseline: 2.0892x; 2.0892x over previous
//
#include <hip/hip_runtime.h>
#include <math.h>

#define SEQ 12
#define NBATCH 16384   // BC*NODES
#define FEAT 32
#define HID 64
#define NSPLIT 4       // KV-split factor for GAT fast path

// ---- fallback packed-weight layout (floats, round-2 format) ----
#define WP_IH0 0
#define WP_HH0 6144
#define WP_IH1 18432
#define WP_HH1 30720
#define WP_TOTAL 43008

typedef __attribute__((ext_vector_type(8))) short bf16x8;   // 8 bf16 = 4 VGPR
typedef __attribute__((ext_vector_type(4))) float f32x4;

#define MFMA_B16(A,B,C) __builtin_amdgcn_mfma_f32_16x16x32_bf16((A),(B),(C),0,0,0)

union B8u { unsigned short s[8]; bf16x8 v; };

__device__ __forceinline__ float sigf(float x) { return 1.0f / (1.0f + __expf(-x)); }
__device__ __forceinline__ float tanh_fast(float x) { return 2.0f / (1.0f + __expf(-2.0f * x)) - 1.0f; }

__device__ __forceinline__ unsigned int packsplit(float v) {
  unsigned int u  = __float_as_uint(v);
  unsigned int hi = u & 0xFFFF0000u;
  unsigned int lo = __float_as_uint(v - __uint_as_float(hi)) >> 16;
  return hi | lo;
}

__device__ __forceinline__ void unpack8(const unsigned int* p, bf16x8& H, bf16x8& L) {
  uint4 u0 = *(const uint4*)p;
  uint4 u1 = *(const uint4*)(p + 4);
  unsigned int uu[8] = {u0.x, u0.y, u0.z, u0.w, u1.x, u1.y, u1.z, u1.w};
  B8u hh, ll;
  #pragma unroll
  for (int i = 0; i < 8; i++) {
    hh.s[i] = (unsigned short)(uu[i] >> 16);
    ll.s[i] = (unsigned short)(uu[i] & 0xFFFFu);
  }
  H = hh.v; L = ll.v;
}

__device__ __forceinline__ void split8(const float* fa, bf16x8& H, bf16x8& L) {
  B8u hh, ll;
  #pragma unroll
  for (int i = 0; i < 8; i++) {
    unsigned int u  = __float_as_uint(fa[i]);
    unsigned int hi = u & 0xFFFF0000u;
    hh.s[i] = (unsigned short)(hi >> 16);
    ll.s[i] = (unsigned short)(__float_as_uint(fa[i] - __uint_as_float(hi)) >> 16);
  }
  H = hh.v; L = ll.v;
}

#define DOT4(acc, A_, B_)                                   \
  acc = fmaf((A_).x, (B_).x, acc);                          \
  acc = fmaf((A_).y, (B_).y, acc);                          \
  acc = fmaf((A_).z, (B_).z, acc);                          \
  acc = fmaf((A_).w, (B_).w, acc);

// ===========================================================================
// Weight pre-pack into MFMA B-fragments (hi/lo planes). Verified rounds 4-13.
// ===========================================================================
__global__ void prep_frag_kernel(const float* __restrict__ w_ih0, const float* __restrict__ w_hh0,
                                 const float* __restrict__ w_ih1, const float* __restrict__ w_hh1,
                                 unsigned short* __restrict__ wf)
{
  int i = blockIdx.x * blockDim.x + threadIdx.x;   // 0..43007
  if (i >= 43008) return;
  const float* src; int K, rel, baseS;
  if (i < 6144)       { src = w_ih0; K = 32; rel = i;         baseS = 0; }
  else if (i < 18432) { src = w_hh0; K = 64; rel = i - 6144;  baseS = 12288; }
  else if (i < 30720) { src = w_ih1; K = 64; rel = i - 18432; baseS = 36864; }
  else                { src = w_hh1; K = 64; rel = i - 30720; baseS = 61440; }
  int nks = K / 32;
  int fp   = rel >> 9;
  int lane = (rel >> 3) & 63;
  int e    = rel & 7;
  int ct = fp / nks, ks = fp % nks;
  int g = ct * 16 + (lane & 15);
  int k = ks * 32 + (lane >> 4) * 8 + e;
  float v = src[g * K + k];
  unsigned int u = __float_as_uint(v);
  unsigned short hi = (unsigned short)(u >> 16);
  float hif = __uint_as_float(u & 0xFFFF0000u);
  unsigned short lo = (unsigned short)(__float_as_uint(v - hif) >> 16);
  int out = baseS + fp * 1024 + lane * 8 + e;
  wf[out]       = hi;
  wf[out + 512] = lo;
}

// mask [1024][1024] int -> bitmask [1024][32] u32 (128KB, L1/L2-hot)
__global__ void mask_pack(const int* __restrict__ mask, unsigned int* __restrict__ mbits)
{
  int i = blockIdx.x * blockDim.x + threadIdx.x;   // 0..32767
  if (i >= 32768) return;
  int r = i >> 5, wd = i & 31;
  const int* mp = mask + (size_t)r * 1024 + wd * 32;
  unsigned int b = 0;
  #pragma unroll
  for (int k = 0; k < 32; k++) b |= (mp[k] != 0 ? 1u : 0u) << k;
  mbits[i] = b;
}

// ===========================================================================
// FUSED 2-layer MFMA GRU v3:
//  - h-state in SEPARATE hi/lo bf16 LDS planes (stride 72 ushort): A-frags are
//    direct ds_read_b128, zero unpack VALU
//  - ONE barrier per t (double-buffer + block rendezvous covers all hazards)
//  - __launch_bounds__(256,2): VGPR budget 256 -> weights stay REGISTER-
//    RESIDENT (round-13 lesson: (256,4) forced 64 VGPR -> scratch spill,
//    860MB refetch, 3.4x regression)
// ===========================================================================
#define HSTR 72
__global__ __launch_bounds__(256, 2) void gru_fused(
    const float* __restrict__ x, const unsigned short* __restrict__ wf,
    const float* __restrict__ b_ih0, const float* __restrict__ b_hh0,
    const float* __restrict__ b_ih1, const float* __restrict__ b_hh1,
    unsigned int* __restrict__ zpk0, unsigned int* __restrict__ zpk1)
{
  __shared__ unsigned short h0h[2][16 * HSTR], h0o[2][16 * HSTR];
  __shared__ unsigned short h1h[2][16 * HSTR], h1o[2][16 * HSTR];
  const int tid = threadIdx.x;
  const int w = tid >> 6, l = tid & 63, lr = l & 15, lg = l >> 4;
  const int s0 = blockIdx.x * 16;
  const int j = w * 16 + lr;

  // ---- B-fragments -> VGPRs (identical addresses across blocks: L2-hot) ----
  bf16x8 Wih0[3][2], Whh0[3][2][2], Wih1[3][2][2], Whh1[3][2][2];
  #pragma unroll
  for (int g = 0; g < 3; g++) {
    const int ct = w + g * 4;
    Wih0[g][0] = *(const bf16x8*)&wf[ct * 1024 + l * 8];
    Wih0[g][1] = *(const bf16x8*)&wf[ct * 1024 + 512 + l * 8];
    #pragma unroll
    for (int ks = 0; ks < 2; ks++) {
      Whh0[g][ks][0] = *(const bf16x8*)&wf[12288 + (ct * 2 + ks) * 1024 + l * 8];
      Whh0[g][ks][1] = *(const bf16x8*)&wf[12288 + (ct * 2 + ks) * 1024 + 512 + l * 8];
      Wih1[g][ks][0] = *(const bf16x8*)&wf[36864 + (ct * 2 + ks) * 1024 + l * 8];
      Wih1[g][ks][1] = *(const bf16x8*)&wf[36864 + (ct * 2 + ks) * 1024 + 512 + l * 8];
      Whh1[g][ks][0] = *(const bf16x8*)&wf[61440 + (ct * 2 + ks) * 1024 + l * 8];
      Whh1[g][ks][1] = *(const bf16x8*)&wf[61440 + (ct * 2 + ks) * 1024 + 512 + l * 8];
    }
  }

  const float br0  = b_ih0[j]      + b_hh0[j];
  const float bz0  = b_ih0[64 + j] + b_hh0[64 + j];
  const float bni0 = b_ih0[128 + j];
  const float bnh0 = b_hh0[128 + j];
  const float br1  = b_ih1[j]      + b_hh1[j];
  const float bz1  = b_ih1[64 + j] + b_hh1[64 + j];
  const float bni1 = b_ih1[128 + j];
  const float bnh1 = b_hh1[128 + j];

  for (int i = tid; i < 16 * HSTR; i += 256) {
    h0h[0][i] = 0; h0o[0][i] = 0; h1h[0][i] = 0; h1o[0][i] = 0;
  }
  float hD0[4] = {0.f, 0.f, 0.f, 0.f};
  float hD1[4] = {0.f, 0.f, 0.f, 0.f};
  __syncthreads();

  float4 xc0 = *(const float4*)(x + ((size_t)s0 + lr) * FEAT + lg * 8);
  float4 xc1 = *(const float4*)(x + ((size_t)s0 + lr) * FEAT + lg * 8 + 4);

  int pb = 0;
  #pragma unroll 1
  for (int t = 0; t < SEQ; t++) {
    const int cb = pb ^ 1;
    float4 xn0, xn1;
    if (t < SEQ - 1) {
      const float* xp = x + ((size_t)(t + 1) * NBATCH + s0 + lr) * FEAT + lg * 8;
      xn0 = *(const float4*)xp;
      xn1 = *(const float4*)(xp + 4);
    }

    // ================= layer 0 =================
    f32x4 aR, aZ, aNI, aNH;
    #pragma unroll
    for (int e = 0; e < 4; e++) { aR[e] = br0; aZ[e] = bz0; aNI[e] = bni0; aNH[e] = bnh0; }
    {
      float fa[8] = {xc0.x, xc0.y, xc0.z, xc0.w, xc1.x, xc1.y, xc1.z, xc1.w};
      bf16x8 Ah, Al;
      split8(fa, Ah, Al);
      aR  = MFMA_B16(Ah, Wih0[0][0], aR);  aR  = MFMA_B16(Al, Wih0[0][0], aR);  aR  = MFMA_B16(Ah, Wih0[0][1], aR);
      aZ  = MFMA_B16(Ah, Wih0[1][0], aZ);  aZ  = MFMA_B16(Al, Wih0[1][0], aZ);  aZ  = MFMA_B16(Ah, Wih0[1][1], aZ);
      aNI = MFMA_B16(Ah, Wih0[2][0], aNI); aNI = MFMA_B16(Al, Wih0[2][0], aNI); aNI = MFMA_B16(Ah, Wih0[2][1], aNI);
    }
    #pragma unroll
    for (int ks = 0; ks < 2; ks++) {
      bf16x8 Ah = *(const bf16x8*)&h0h[pb][lr * HSTR + ks * 32 + lg * 8];
      bf16x8 Al = *(const bf16x8*)&h0o[pb][lr * HSTR + ks * 32 + lg * 8];
      aR  = MFMA_B16(Ah, Whh0[0][ks][0], aR);  aR  = MFMA_B16(Al, Whh0[0][ks][0], aR);  aR  = MFMA_B16(Ah, Whh0[0][ks][1], aR);
      aZ  = MFMA_B16(Ah, Whh0[1][ks][0], aZ);  aZ  = MFMA_B16(Al, Whh0[1][ks][0], aZ);  aZ  = MFMA_B16(Ah, Whh0[1][ks][1], aZ);
      aNH = MFMA_B16(Ah, Whh0[2][ks][0], aNH); aNH = MFMA_B16(Al, Whh0[2][ks][0], aNH); aNH = MFMA_B16(Ah, Whh0[2][ks][1], aNH);
    }
    #pragma unroll
    for (int e = 0; e < 4; e++) {
      float rg = sigf(aR[e]);
      float zg = sigf(aZ[e]);
      float n  = tanh_fast(fmaf(rg, aNH[e], aNI[e]));
      float hn = fmaf(zg, hD0[e] - n, n);
      hD0[e] = hn;
      unsigned int pk = packsplit(hn);
      int idx = (lg * 4 + e) * HSTR + j;
      h0h[cb][idx] = (unsigned short)(pk >> 16);
      h0o[cb][idx] = (unsigned short)(pk & 0xFFFFu);
    }
    __syncthreads();   // h0_new visible; also orders all cross-t hazards

    // ================= layer 1 =================
    #pragma unroll
    for (int e = 0; e < 4; e++) { aR[e] = br1; aZ[e] = bz1; aNI[e] = bni1; aNH[e] = bnh1; }
    #pragma unroll
    for (int ks = 0; ks < 2; ks++) {
      bf16x8 Ah = *(const bf16x8*)&h0h[cb][lr * HSTR + ks * 32 + lg * 8];
      bf16x8 Al = *(const bf16x8*)&h0o[cb][lr * HSTR + ks * 32 + lg * 8];
      aR  = MFMA_B16(Ah, Wih1[0][ks][0], aR);  aR  = MFMA_B16(Al, Wih1[0][ks][0], aR);  aR  = MFMA_B16(Ah, Wih1[0][ks][1], aR);
      aZ  = MFMA_B16(Ah, Wih1[1][ks][0], aZ);  aZ  = MFMA_B16(Al, Wih1[1][ks][0], aZ);  aZ  = MFMA_B16(Ah, Wih1[1][ks][1], aZ);
      aNI = MFMA_B16(Ah, Wih1[2][ks][0], aNI); aNI = MFMA_B16(Al, Wih1[2][ks][0], aNI); aNI = MFMA_B16(Ah, Wih1[2][ks][1], aNI);
    }
    #pragma unroll
    for (int ks = 0; ks < 2; ks++) {
      bf16x8 Ah = *(const bf16x8*)&h1h[pb][lr * HSTR + ks * 32 + lg * 8];
      bf16x8 Al = *(const bf16x8*)&h1o[pb][lr * HSTR + ks * 32 + lg * 8];
      aR  = MFMA_B16(Ah, Whh1[0][ks][0], aR);  aR  = MFMA_B16(Al, Whh1[0][ks][0], aR);  aR  = MFMA_B16(Ah, Whh1[0][ks][1], aR);
      aZ  = MFMA_B16(Ah, Whh1[1][ks][0], aZ);  aZ  = MFMA_B16(Al, Whh1[1][ks][0], aZ);  aZ  = MFMA_B16(Ah, Whh1[1][ks][1], aZ);
      aNH = MFMA_B16(Ah, Whh1[2][ks][0], aNH); aNH = MFMA_B16(Al, Whh1[2][ks][0], aNH); aNH = MFMA_B16(Ah, Whh1[2][ks][1], aNH);
    }
    #pragma unroll
    for (int e = 0; e < 4; e++) {
      float rg = sigf(aR[e]);
      float zg = sigf(aZ[e]);
      float n  = tanh_fast(fmaf(rg, aNH[e], aNI[e]));
      float hn = fmaf(zg, hD1[e] - n, n);
      hD1[e] = hn;
      unsigned int pk = packsplit(hn);
      int idx = (lg * 4 + e) * HSTR + j;
      h1h[cb][idx] = (unsigned short)(pk >> 16);
      h1o[cb][idx] = (unsigned short)(pk & 0xFFFFu);
    }
    // no end-of-t barrier: next t's mid-barrier orders all remaining hazards
    xc0 = xn0; xc1 = xn1;
    pb = cb;
  }

  #pragma unroll
  for (int e = 0; e < 4; e++) {
    int sl = lg * 4 + e;
    zpk0[(size_t)(s0 + sl) * 64 + j] = packsplit(hD0[e]);
    zpk1[(size_t)(s0 + sl) * 64 + j] = packsplit(hD1[e]);
  }
}

// ===========================================================================
// FALLBACK (small ws): round-2 LDS-weight GRU, writes PACKED z
// ===========================================================================
__global__ void prep_kernel(const float* __restrict__ w_ih0, const float* __restrict__ w_hh0,
                            const float* __restrict__ w_ih1, const float* __restrict__ w_hh1,
                            float* __restrict__ wp)
{
  for (int i = blockIdx.x * blockDim.x + threadIdx.x; i < WP_TOTAL; i += gridDim.x * blockDim.x) {
    const float* src;
    int K, rel;
    if (i < WP_HH0)      { src = w_ih0; K = 32; rel = i; }
    else if (i < WP_IH1) { src = w_hh0; K = 64; rel = i - WP_HH0; }
    else if (i < WP_HH1) { src = w_ih1; K = 64; rel = i - WP_IH1; }
    else                 { src = w_hh1; K = 64; rel = i - WP_HH1; }
    int kr = rel & 3;
    int jj = (rel >> 2) & 63;
    int rest = rel >> 8;
    int g = rest % 3;
    int k4 = rest / 3;
    wp[i] = src[(g * 64 + jj) * K + k4 * 4 + kr];
  }
}

__global__ __launch_bounds__(256, 1) void gru_fallback(
    const float* __restrict__ x, const float* __restrict__ wpack,
    const float* __restrict__ b_ih0, const float* __restrict__ b_hh0,
    const float* __restrict__ b_ih1, const float* __restrict__ b_hh1,
    unsigned int* __restrict__ zout)
{
  __shared__ float wlds[36864];
  __shared__ float h0s[16][64];
  __shared__ float h1s[16][64];
  const int tid = threadIdx.x;
  {
    const float4* src = (const float4*)(wpack + WP_HH0);
    float4* dst = (float4*)wlds;
    #pragma unroll 4
    for (int i = tid; i < 9216; i += 256) dst[i] = src[i];
  }
  const int j  = tid & 63;
  const int sg = __builtin_amdgcn_readfirstlane(tid >> 6);
  const float br0  = b_ih0[j]      + b_hh0[j];
  const float bz0  = b_ih0[64 + j] + b_hh0[64 + j];
  const float bni0 = b_ih0[128 + j];
  const float bnh0 = b_hh0[128 + j];
  const float br1  = b_ih1[j]      + b_hh1[j];
  const float bz1  = b_ih1[64 + j] + b_hh1[64 + j];
  const float bni1 = b_ih1[128 + j];
  const float bnh1 = b_hh1[128 + j];
  const int s0 = blockIdx.x * 16;
  float h0r[4] = {0.f, 0.f, 0.f, 0.f};
  float h1r[4] = {0.f, 0.f, 0.f, 0.f};
  #pragma unroll
  for (int ss = 0; ss < 4; ss++) { h0s[sg * 4 + ss][j] = 0.f; h1s[sg * 4 + ss][j] = 0.f; }
  __syncthreads();
  const float4* wih0g = (const float4*)(wpack + WP_IH0);
  const float4* whh0l = (const float4*)(wlds);
  const float4* wih1l = (const float4*)(wlds + 12288);
  const float4* whh1l = (const float4*)(wlds + 24576);
  for (int t = 0; t < SEQ; t++) {
    float ar[4], az[4], ani[4], anh[4];
    #pragma unroll
    for (int ss = 0; ss < 4; ss++) { ar[ss] = br0; az[ss] = bz0; ani[ss] = bni0; anh[ss] = bnh0; }
    const float4* xr0 = (const float4*)(x + ((size_t)t * NBATCH + (s0 + sg * 4 + 0)) * FEAT);
    const float4* xr1 = (const float4*)(x + ((size_t)t * NBATCH + (s0 + sg * 4 + 1)) * FEAT);
    const float4* xr2 = (const float4*)(x + ((size_t)t * NBATCH + (s0 + sg * 4 + 2)) * FEAT);
    const float4* xr3 = (const float4*)(x + ((size_t)t * NBATCH + (s0 + sg * 4 + 3)) * FEAT);
    #pragma unroll
    for (int k4 = 0; k4 < 8; k4++) {
      float4 wr = wih0g[(k4 * 3 + 0) * 64 + j];
      float4 wz = wih0g[(k4 * 3 + 1) * 64 + j];
      float4 wn = wih0g[(k4 * 3 + 2) * 64 + j];
      float4 xv[4] = {xr0[k4], xr1[k4], xr2[k4], xr3[k4]};
      #pragma unroll
      for (int ss = 0; ss < 4; ss++) {
        DOT4(ar[ss],  wr, xv[ss]);
        DOT4(az[ss],  wz, xv[ss]);
        DOT4(ani[ss], wn, xv[ss]);
      }
    }
    #pragma unroll
    for (int k4 = 0; k4 < 16; k4++) {
      float4 wr = whh0l[(k4 * 3 + 0) * 64 + j];
      float4 wz = whh0l[(k4 * 3 + 1) * 64 + j];
      float4 wn = whh0l[(k4 * 3 + 2) * 64 + j];
      #pragma unroll
      for (int ss = 0; ss < 4; ss++) {
        float4 hv = *(const float4*)&h0s[sg * 4 + ss][k4 * 4];
        DOT4(ar[ss],  wr, hv);
        DOT4(az[ss],  wz, hv);
        DOT4(anh[ss], wn, hv);
      }
    }
    float h0n[4];
    #pragma unroll
    for (int ss = 0; ss < 4; ss++) {
      float rg = sigf(ar[ss]);
      float zg = sigf(az[ss]);
      float ng = tanh_fast(fmaf(rg, anh[ss], ani[ss]));
      h0n[ss] = fmaf(zg, h0r[ss] - ng, ng);
    }
    __syncthreads();
    #pragma unroll
    for (int ss = 0; ss < 4; ss++) { h0s[sg * 4 + ss][j] = h0n[ss]; h0r[ss] = h0n[ss]; }
    __syncthreads();
    #pragma unroll
    for (int ss = 0; ss < 4; ss++) { ar[ss] = br1; az[ss] = bz1; ani[ss] = bni1; anh[ss] = bnh1; }
    #pragma unroll
    for (int k4 = 0; k4 < 16; k4++) {
      float4 wr = wih1l[(k4 * 3 + 0) * 64 + j];
      float4 wz = wih1l[(k4 * 3 + 1) * 64 + j];
      float4 wn = wih1l[(k4 * 3 + 2) * 64 + j];
      #pragma unroll
      for (int ss = 0; ss < 4; ss++) {
        float4 hv = *(const float4*)&h0s[sg * 4 + ss][k4 * 4];
        DOT4(ar[ss],  wr, hv);
        DOT4(az[ss],  wz, hv);
        DOT4(ani[ss], wn, hv);
      }
    }
    #pragma unroll
    for (int k4 = 0; k4 < 16; k4++) {
      float4 wr = whh1l[(k4 * 3 + 0) * 64 + j];
      float4 wz = whh1l[(k4 * 3 + 1) * 64 + j];
      float4 wn = whh1l[(k4 * 3 + 2) * 64 + j];
      #pragma unroll
      for (int ss = 0; ss < 4; ss++) {
        float4 hv = *(const float4*)&h1s[sg * 4 + ss][k4 * 4];
        DOT4(ar[ss],  wr, hv);
        DOT4(az[ss],  wz, hv);
        DOT4(anh[ss], wn, hv);
      }
    }
    float h1n[4];
    #pragma unroll
    for (int ss = 0; ss < 4; ss++) {
      float rg = sigf(ar[ss]);
      float zg = sigf(az[ss]);
      float ng = tanh_fast(fmaf(rg, anh[ss], ani[ss]));
      h1n[ss] = fmaf(zg, h1r[ss] - ng, ng);
    }
    __syncthreads();
    #pragma unroll
    for (int ss = 0; ss < 4; ss++) { h1s[sg * 4 + ss][j] = h1n[ss]; h1r[ss] = h1n[ss]; }
    __syncthreads();
  }
  #pragma unroll
  for (int ss = 0; ss < 4; ss++) {
    int s = s0 + sg * 4 + ss;
    zout[(size_t)s * 64 + j]            = packsplit(h0r[ss]);
    zout[(size_t)(NBATCH + s) * 64 + j] = packsplit(h1r[ss]);
  }
}

// ===========================================================================
// MFMA GAT v4 (verified round 10): KV-split flash attention, fixed-max softmax.
// ===========================================================================
__global__ __launch_bounds__(256, 4) void gat_mfma4(
    const unsigned int* __restrict__ zpk, const unsigned int* __restrict__ mbits,
    float* __restrict__ partO, float* __restrict__ partD,
    float* __restrict__ out, int nsplit)
{
  __shared__ unsigned int VT[64 * 68];   // packed hi|lo, [d][s] layout
  __shared__ float        PS[64 * 68];   // P fp32, wave-private rows
  const int tid = threadIdx.x;
  const int w = tid >> 6, l = tid & 63, lr = l & 15, lg = l >> 4;
  const int blk  = blockIdx.x;
  const int lbrt = blk / nsplit;
  const int half = blk - lbrt * nsplit;
  const int rt = lbrt & 15;
  const int lb = lbrt >> 4;
  const int tiles = 16 / nsplit;
  const int mt0 = half * tiles;
  const unsigned int* zb = zpk + (size_t)lb * 65536;
  const int n0 = rt * 64;

  bf16x8 Qh[2], Ql[2];
  #pragma unroll
  for (int ks = 0; ks < 2; ks++)
    unpack8(&zb[(size_t)(n0 + w * 16 + lr) * 64 + ks * 32 + lg * 8], Qh[ks], Ql[ks]);

  f32x4 O[4];
  float D[4] = {0.f, 0.f, 0.f, 0.f};
  #pragma unroll
  for (int ct = 0; ct < 4; ct++)
    #pragma unroll
    for (int e = 0; e < 4; e++) O[ct][e] = 0.f;

  #pragma unroll 1
  for (int mt = mt0; mt < mt0 + tiles; ++mt) {
    __syncthreads();
    {
      unsigned int tmp[16];
      #pragma unroll
      for (int r = 0; r < 16; r++)
        tmp[r] = zb[(size_t)(mt * 64 + w * 16 + r) * 64 + l];
      #pragma unroll
      for (int q = 0; q < 4; q++)
        *(uint4*)&VT[l * 68 + w * 16 + q * 4] =
            make_uint4(tmp[q * 4], tmp[q * 4 + 1], tmp[q * 4 + 2], tmp[q * 4 + 3]);
    }
    __syncthreads();

    // S = Q.K^T (3-term split, full precision through exp)
    f32x4 S[4];
    #pragma unroll
    for (int ct = 0; ct < 4; ct++)
      #pragma unroll
      for (int e = 0; e < 4; e++) S[ct][e] = 0.f;
    #pragma unroll
    for (int ks = 0; ks < 2; ks++) {
      #pragma unroll
      for (int ct = 0; ct < 4; ct++) {
        bf16x8 Kh, Kl;
        unpack8(&zb[(size_t)(mt * 64 + ct * 16 + lr) * 64 + ks * 32 + lg * 8], Kh, Kl);
        S[ct] = MFMA_B16(Qh[ks], Kh, S[ct]);
        S[ct] = MFMA_B16(Ql[ks], Kh, S[ct]);
        S[ct] = MFMA_B16(Qh[ks], Kl, S[ct]);
      }
    }

    // fixed-max masked softmax: P = exp(leaky(S)-64), masked/zero -> 0
    #pragma unroll
    for (int e = 0; e < 4; e++) {
      const int row = n0 + w * 16 + lg * 4 + e;
      const uint2 mw = *(const uint2*)&mbits[(size_t)row * 32 + mt * 2];
      const unsigned int sel[4] = {mw.x >> lr, mw.x >> (16 + lr), mw.y >> lr, mw.y >> (16 + lr)};
      float ds = 0.f;
      #pragma unroll
      for (int ct = 0; ct < 4; ct++) {
        float v = S[ct][e];
        float lrv = v > 0.f ? v : 0.1f * v;
        float p = ((sel[ct] & 1u) && lrv != 0.0f) ? __expf(lrv - 64.0f) : 0.0f;
        ds += p;
        PS[(w * 16 + lg * 4 + e) * 68 + ct * 16 + lr] = p;
      }
      D[e] += ds;
    }

    // O += P.V  (P bf16-RNE single term; V full hi+lo)
    #pragma unroll
    for (int ks = 0; ks < 2; ks++) {
      const float* pp = &PS[(w * 16 + lr) * 68 + ks * 32 + lg * 8];
      float4 p0 = *(const float4*)pp;
      float4 p1 = *(const float4*)(pp + 4);
      float fa[8] = {p0.x, p0.y, p0.z, p0.w, p1.x, p1.y, p1.z, p1.w};
      B8u H;
      #pragma unroll
      for (int i = 0; i < 8; i++)
        H.s[i] = (unsigned short)((__float_as_uint(fa[i]) + 0x8000u) >> 16);
      bf16x8 Ph = H.v;
      #pragma unroll
      for (int ct = 0; ct < 4; ct++) {
        bf16x8 Vh, Vl;
        unpack8(&VT[(ct * 16 + lr) * 68 + ks * 32 + lg * 8], Vh, Vl);
        O[ct] = MFMA_B16(Ph, Vh, O[ct]);
        O[ct] = MFMA_B16(Ph, Vl, O[ct]);
      }
    }
  }

  // reduce D across the 16 lanes of each row group (once, not per-mt)
  #pragma unroll
  for (int e = 0; e < 4; e++) {
    #pragma unroll
    for (int sw = 1; sw < 16; sw <<= 1) D[e] += __shfl_xor(D[e], sw, 16);
  }

  if (nsplit == 1) {
    #pragma unroll
    for (int e = 0; e < 4; e++) {
      float inv = 1.0f / D[e];
      size_t rowo = ((size_t)lb * 1024 + n0 + w * 16 + lg * 4 + e) * 64;
      #pragma unroll
      for (int ct = 0; ct < 4; ct++)
        out[rowo + ct * 16 + lr] = O[ct][e] * inv;
    }
  } else {
    float* po = partO + (size_t)blk * 4096;
    #pragma unroll
    for (int e = 0; e < 4; e++) {
      int row = w * 16 + lg * 4 + e;
      #pragma unroll
      for (int ct = 0; ct < 4; ct++)
        po[row * 64 + ct * 16 + lr] = O[ct][e];
      if (lr == 0) partD[(size_t)blk * 64 + row] = D[e];
    }
  }
}

// merge: out = sum_i O_i / sum_i D_i  (fixed max -> plain sums, no exp)
__global__ __launch_bounds__(256) void gat_combine(
    const float* __restrict__ partO, const float* __restrict__ partD,
    float* __restrict__ out, int nsplit)
{
  const int lbrt = blockIdx.x;             // 0..511
  const int q  = threadIdx.x >> 2;         // 0..63
  const int dc = (threadIdx.x & 3) * 16;   // 0,16,32,48
  float dt = 0.f;
  for (int i = 0; i < nsplit; i++) dt += partD[(size_t)(lbrt * nsplit + i) * 64 + q];
  float inv = 1.0f / dt;
  float* op = out + ((size_t)lbrt * 64 + q) * 64 + dc;
  #pragma unroll
  for (int v = 0; v < 4; v++) {
    float4 acc = make_float4(0.f, 0.f, 0.f, 0.f);
    for (int i = 0; i < nsplit; i++) {
      const float4 o = *(const float4*)(partO + (size_t)(lbrt * nsplit + i) * 4096 + q * 64 + dc + v * 4);
      acc.x += o.x; acc.y += o.y; acc.z += o.z; acc.w += o.w;
    }
    *(float4*)(op + v * 4) = make_float4(acc.x * inv, acc.y * inv, acc.z * inv, acc.w * inv);
  }
}

extern "C" void kernel_launch(void* const* d_in, const int* in_sizes, int n_in,
                              void* d_out, int out_size, void* d_ws, size_t ws_size,
                              hipStream_t stream) {
  const float* h     = (const float*)d_in[0];
  const int*   mask  = (const int*)d_in[1];
  const float* w_ih0 = (const float*)d_in[2];
  const float* w_hh0 = (const float*)d_in[3];
  const float* b_ih0 = (const float*)d_in[4];
  const float* b_hh0 = (const float*)d_in[5];
  const float* w_ih1 = (const float*)d_in[6];
  const float* w_hh1 = (const float*)d_in[7];
  const float* b_ih1 = (const float*)d_in[8];
  const float* b_hh1 = (const float*)d_in[9];
  float* out = (float*)d_out;

  char* wsb = (char*)d_ws;
  unsigned int* zpk = (unsigned int*)wsb;                     // [2][16384][64] packed u32
  const size_t Z_BYTES  = (size_t)2 * NBATCH * 64 * 4;        // 8388608
  const size_t PART_OFF = Z_BYTES + 176128;                   // past 172KB frag weights
  const size_t PO_BYTES = (size_t)512 * NSPLIT * 4096 * 4;    // 33.6MB
  const size_t PD_BYTES = (size_t)512 * NSPLIT * 64 * 4;      // 512KB
  const size_t MB_OFF   = PART_OFF + PO_BYTES + PD_BYTES;
  const size_t NEED_FAST = MB_OFF + 131072;

  if (ws_size >= NEED_FAST) {
    unsigned short* wfrag = (unsigned short*)(wsb + Z_BYTES);
    float* partO  = (float*)(wsb + PART_OFF);
    float* partD  = (float*)(wsb + PART_OFF + PO_BYTES);
    unsigned int* mbits = (unsigned int*)(wsb + MB_OFF);
    prep_frag_kernel<<<168, 256, 0, stream>>>(w_ih0, w_hh0, w_ih1, w_hh1, wfrag);
    mask_pack<<<128, 256, 0, stream>>>(mask, mbits);
    gru_fused<<<1024, 256, 0, stream>>>(h, wfrag, b_ih0, b_hh0, b_ih1, b_hh1,
                                        zpk, zpk + (size_t)NBATCH * 64);
    gat_mfma4<<<512 * NSPLIT, 256, 0, stream>>>(zpk, mbits, partO, partD, out, NSPLIT);
    gat_combine<<<512, 256, 0, stream>>>(partO, partD, out, NSPLIT);
  } else {
    float* wpack = (float*)(wsb + Z_BYTES);
    unsigned int* mbits = (unsigned int*)(wsb + Z_BYTES + 172032);
    prep_kernel<<<24, 256, 0, stream>>>(w_ih0, w_hh0, w_ih1, w_hh1, wpack);
    mask_pack<<<128, 256, 0, stream>>>(mask, mbits);
    gru_fallback<<<1024, 256, 0, stream>>>(h, wpack, b_ih0, b_hh0, b_ih1, b_hh1, zpk);
    gat_mfma4<<<512, 256, 0, stream>>>(zpk, mbits, nullptr, nullptr, out, 1);
  }
}

// Round 15
// 167.345 us; speedup vs baseline: 2.2641x; 1.0837x over previous
//
#include <hip/hip_runtime.h>
#include <math.h>

#define SEQ 12
#define NBATCH 16384   // BC*NODES
#define FEAT 32
#define HID 64
#define NSPLIT 2       // KV-split factor: grid 1024 = exactly 1 round at 4 blk/CU

// ---- fallback packed-weight layout (floats, round-2 format) ----
#define WP_IH0 0
#define WP_HH0 6144
#define WP_IH1 18432
#define WP_HH1 30720
#define WP_TOTAL 43008

typedef __attribute__((ext_vector_type(8))) short bf16x8;   // 8 bf16 = 4 VGPR
typedef __attribute__((ext_vector_type(4))) float f32x4;

#define MFMA_B16(A,B,C) __builtin_amdgcn_mfma_f32_16x16x32_bf16((A),(B),(C),0,0,0)

union B8u { unsigned short s[8]; bf16x8 v; };

__device__ __forceinline__ float sigf(float x) { return 1.0f / (1.0f + __expf(-x)); }
__device__ __forceinline__ float tanh_fast(float x) { return 2.0f / (1.0f + __expf(-2.0f * x)) - 1.0f; }

__device__ __forceinline__ unsigned int packsplit(float v) {
  unsigned int u  = __float_as_uint(v);
  unsigned int hi = u & 0xFFFF0000u;
  unsigned int lo = __float_as_uint(v - __uint_as_float(hi)) >> 16;
  return hi | lo;
}

__device__ __forceinline__ void unpack8(const unsigned int* p, bf16x8& H, bf16x8& L) {
  uint4 u0 = *(const uint4*)p;
  uint4 u1 = *(const uint4*)(p + 4);
  unsigned int uu[8] = {u0.x, u0.y, u0.z, u0.w, u1.x, u1.y, u1.z, u1.w};
  B8u hh, ll;
  #pragma unroll
  for (int i = 0; i < 8; i++) {
    hh.s[i] = (unsigned short)(uu[i] >> 16);
    ll.s[i] = (unsigned short)(uu[i] & 0xFFFFu);
  }
  H = hh.v; L = ll.v;
}

__device__ __forceinline__ void split8(const float* fa, bf16x8& H, bf16x8& L) {
  B8u hh, ll;
  #pragma unroll
  for (int i = 0; i < 8; i++) {
    unsigned int u  = __float_as_uint(fa[i]);
    unsigned int hi = u & 0xFFFF0000u;
    hh.s[i] = (unsigned short)(hi >> 16);
    ll.s[i] = (unsigned short)(__float_as_uint(fa[i] - __uint_as_float(hi)) >> 16);
  }
  H = hh.v; L = ll.v;
}

#define DOT4(acc, A_, B_)                                   \
  acc = fmaf((A_).x, (B_).x, acc);                          \
  acc = fmaf((A_).y, (B_).y, acc);                          \
  acc = fmaf((A_).z, (B_).z, acc);                          \
  acc = fmaf((A_).w, (B_).w, acc);

// ===========================================================================
// Weight pre-pack into MFMA B-fragments (hi/lo planes). Verified rounds 4-14.
// ===========================================================================
__global__ void prep_frag_kernel(const float* __restrict__ w_ih0, const float* __restrict__ w_hh0,
                                 const float* __restrict__ w_ih1, const float* __restrict__ w_hh1,
                                 unsigned short* __restrict__ wf)
{
  int i = blockIdx.x * blockDim.x + threadIdx.x;   // 0..43007
  if (i >= 43008) return;
  const float* src; int K, rel, baseS;
  if (i < 6144)       { src = w_ih0; K = 32; rel = i;         baseS = 0; }
  else if (i < 18432) { src = w_hh0; K = 64; rel = i - 6144;  baseS = 12288; }
  else if (i < 30720) { src = w_ih1; K = 64; rel = i - 18432; baseS = 36864; }
  else                { src = w_hh1; K = 64; rel = i - 30720; baseS = 61440; }
  int nks = K / 32;
  int fp   = rel >> 9;
  int lane = (rel >> 3) & 63;
  int e    = rel & 7;
  int ct = fp / nks, ks = fp % nks;
  int g = ct * 16 + (lane & 15);
  int k = ks * 32 + (lane >> 4) * 8 + e;
  float v = src[g * K + k];
  unsigned int u = __float_as_uint(v);
  unsigned short hi = (unsigned short)(u >> 16);
  float hif = __uint_as_float(u & 0xFFFF0000u);
  unsigned short lo = (unsigned short)(__float_as_uint(v - hif) >> 16);
  int out = baseS + fp * 1024 + lane * 8 + e;
  wf[out]       = hi;
  wf[out + 512] = lo;
}

// mask [1024][1024] int -> bitmask [1024][32] u32 (128KB, L1/L2-hot)
__global__ void mask_pack(const int* __restrict__ mask, unsigned int* __restrict__ mbits)
{
  int i = blockIdx.x * blockDim.x + threadIdx.x;   // 0..32767
  if (i >= 32768) return;
  int r = i >> 5, wd = i & 31;
  const int* mp = mask + (size_t)r * 1024 + wd * 32;
  unsigned int b = 0;
  #pragma unroll
  for (int k = 0; k < 32; k++) b |= (mp[k] != 0 ? 1u : 0u) << k;
  mbits[i] = b;
}

// ===========================================================================
// FUSED 2-layer MFMA GRU v3 (verified round 14: 88us, VGPR 128, no spill).
// ===========================================================================
#define HSTR 72
__global__ __launch_bounds__(256, 2) void gru_fused(
    const float* __restrict__ x, const unsigned short* __restrict__ wf,
    const float* __restrict__ b_ih0, const float* __restrict__ b_hh0,
    const float* __restrict__ b_ih1, const float* __restrict__ b_hh1,
    unsigned int* __restrict__ zpk0, unsigned int* __restrict__ zpk1)
{
  __shared__ unsigned short h0h[2][16 * HSTR], h0o[2][16 * HSTR];
  __shared__ unsigned short h1h[2][16 * HSTR], h1o[2][16 * HSTR];
  const int tid = threadIdx.x;
  const int w = tid >> 6, l = tid & 63, lr = l & 15, lg = l >> 4;
  const int s0 = blockIdx.x * 16;
  const int j = w * 16 + lr;

  // ---- B-fragments -> VGPRs (identical addresses across blocks: L2-hot) ----
  bf16x8 Wih0[3][2], Whh0[3][2][2], Wih1[3][2][2], Whh1[3][2][2];
  #pragma unroll
  for (int g = 0; g < 3; g++) {
    const int ct = w + g * 4;
    Wih0[g][0] = *(const bf16x8*)&wf[ct * 1024 + l * 8];
    Wih0[g][1] = *(const bf16x8*)&wf[ct * 1024 + 512 + l * 8];
    #pragma unroll
    for (int ks = 0; ks < 2; ks++) {
      Whh0[g][ks][0] = *(const bf16x8*)&wf[12288 + (ct * 2 + ks) * 1024 + l * 8];
      Whh0[g][ks][1] = *(const bf16x8*)&wf[12288 + (ct * 2 + ks) * 1024 + 512 + l * 8];
      Wih1[g][ks][0] = *(const bf16x8*)&wf[36864 + (ct * 2 + ks) * 1024 + l * 8];
      Wih1[g][ks][1] = *(const bf16x8*)&wf[36864 + (ct * 2 + ks) * 1024 + 512 + l * 8];
      Whh1[g][ks][0] = *(const bf16x8*)&wf[61440 + (ct * 2 + ks) * 1024 + l * 8];
      Whh1[g][ks][1] = *(const bf16x8*)&wf[61440 + (ct * 2 + ks) * 1024 + 512 + l * 8];
    }
  }

  const float br0  = b_ih0[j]      + b_hh0[j];
  const float bz0  = b_ih0[64 + j] + b_hh0[64 + j];
  const float bni0 = b_ih0[128 + j];
  const float bnh0 = b_hh0[128 + j];
  const float br1  = b_ih1[j]      + b_hh1[j];
  const float bz1  = b_ih1[64 + j] + b_hh1[64 + j];
  const float bni1 = b_ih1[128 + j];
  const float bnh1 = b_hh1[128 + j];

  for (int i = tid; i < 16 * HSTR; i += 256) {
    h0h[0][i] = 0; h0o[0][i] = 0; h1h[0][i] = 0; h1o[0][i] = 0;
  }
  float hD0[4] = {0.f, 0.f, 0.f, 0.f};
  float hD1[4] = {0.f, 0.f, 0.f, 0.f};
  __syncthreads();

  float4 xc0 = *(const float4*)(x + ((size_t)s0 + lr) * FEAT + lg * 8);
  float4 xc1 = *(const float4*)(x + ((size_t)s0 + lr) * FEAT + lg * 8 + 4);

  int pb = 0;
  #pragma unroll 1
  for (int t = 0; t < SEQ; t++) {
    const int cb = pb ^ 1;
    float4 xn0, xn1;
    if (t < SEQ - 1) {
      const float* xp = x + ((size_t)(t + 1) * NBATCH + s0 + lr) * FEAT + lg * 8;
      xn0 = *(const float4*)xp;
      xn1 = *(const float4*)(xp + 4);
    }

    // ================= layer 0 =================
    f32x4 aR, aZ, aNI, aNH;
    #pragma unroll
    for (int e = 0; e < 4; e++) { aR[e] = br0; aZ[e] = bz0; aNI[e] = bni0; aNH[e] = bnh0; }
    {
      float fa[8] = {xc0.x, xc0.y, xc0.z, xc0.w, xc1.x, xc1.y, xc1.z, xc1.w};
      bf16x8 Ah, Al;
      split8(fa, Ah, Al);
      aR  = MFMA_B16(Ah, Wih0[0][0], aR);  aR  = MFMA_B16(Al, Wih0[0][0], aR);  aR  = MFMA_B16(Ah, Wih0[0][1], aR);
      aZ  = MFMA_B16(Ah, Wih0[1][0], aZ);  aZ  = MFMA_B16(Al, Wih0[1][0], aZ);  aZ  = MFMA_B16(Ah, Wih0[1][1], aZ);
      aNI = MFMA_B16(Ah, Wih0[2][0], aNI); aNI = MFMA_B16(Al, Wih0[2][0], aNI); aNI = MFMA_B16(Ah, Wih0[2][1], aNI);
    }
    #pragma unroll
    for (int ks = 0; ks < 2; ks++) {
      bf16x8 Ah = *(const bf16x8*)&h0h[pb][lr * HSTR + ks * 32 + lg * 8];
      bf16x8 Al = *(const bf16x8*)&h0o[pb][lr * HSTR + ks * 32 + lg * 8];
      aR  = MFMA_B16(Ah, Whh0[0][ks][0], aR);  aR  = MFMA_B16(Al, Whh0[0][ks][0], aR);  aR  = MFMA_B16(Ah, Whh0[0][ks][1], aR);
      aZ  = MFMA_B16(Ah, Whh0[1][ks][0], aZ);  aZ  = MFMA_B16(Al, Whh0[1][ks][0], aZ);  aZ  = MFMA_B16(Ah, Whh0[1][ks][1], aZ);
      aNH = MFMA_B16(Ah, Whh0[2][ks][0], aNH); aNH = MFMA_B16(Al, Whh0[2][ks][0], aNH); aNH = MFMA_B16(Ah, Whh0[2][ks][1], aNH);
    }
    #pragma unroll
    for (int e = 0; e < 4; e++) {
      float rg = sigf(aR[e]);
      float zg = sigf(aZ[e]);
      float n  = tanh_fast(fmaf(rg, aNH[e], aNI[e]));
      float hn = fmaf(zg, hD0[e] - n, n);
      hD0[e] = hn;
      unsigned int pk = packsplit(hn);
      int idx = (lg * 4 + e) * HSTR + j;
      h0h[cb][idx] = (unsigned short)(pk >> 16);
      h0o[cb][idx] = (unsigned short)(pk & 0xFFFFu);
    }
    __syncthreads();   // h0_new visible; also orders all cross-t hazards

    // ================= layer 1 =================
    #pragma unroll
    for (int e = 0; e < 4; e++) { aR[e] = br1; aZ[e] = bz1; aNI[e] = bni1; aNH[e] = bnh1; }
    #pragma unroll
    for (int ks = 0; ks < 2; ks++) {
      bf16x8 Ah = *(const bf16x8*)&h0h[cb][lr * HSTR + ks * 32 + lg * 8];
      bf16x8 Al = *(const bf16x8*)&h0o[cb][lr * HSTR + ks * 32 + lg * 8];
      aR  = MFMA_B16(Ah, Wih1[0][ks][0], aR);  aR  = MFMA_B16(Al, Wih1[0][ks][0], aR);  aR  = MFMA_B16(Ah, Wih1[0][ks][1], aR);
      aZ  = MFMA_B16(Ah, Wih1[1][ks][0], aZ);  aZ  = MFMA_B16(Al, Wih1[1][ks][0], aZ);  aZ  = MFMA_B16(Ah, Wih1[1][ks][1], aZ);
      aNI = MFMA_B16(Ah, Wih1[2][ks][0], aNI); aNI = MFMA_B16(Al, Wih1[2][ks][0], aNI); aNI = MFMA_B16(Ah, Wih1[2][ks][1], aNI);
    }
    #pragma unroll
    for (int ks = 0; ks < 2; ks++) {
      bf16x8 Ah = *(const bf16x8*)&h1h[pb][lr * HSTR + ks * 32 + lg * 8];
      bf16x8 Al = *(const bf16x8*)&h1o[pb][lr * HSTR + ks * 32 + lg * 8];
      aR  = MFMA_B16(Ah, Whh1[0][ks][0], aR);  aR  = MFMA_B16(Al, Whh1[0][ks][0], aR);  aR  = MFMA_B16(Ah, Whh1[0][ks][1], aR);
      aZ  = MFMA_B16(Ah, Whh1[1][ks][0], aZ);  aZ  = MFMA_B16(Al, Whh1[1][ks][0], aZ);  aZ  = MFMA_B16(Ah, Whh1[1][ks][1], aZ);
      aNH = MFMA_B16(Ah, Whh1[2][ks][0], aNH); aNH = MFMA_B16(Al, Whh1[2][ks][0], aNH); aNH = MFMA_B16(Ah, Whh1[2][ks][1], aNH);
    }
    #pragma unroll
    for (int e = 0; e < 4; e++) {
      float rg = sigf(aR[e]);
      float zg = sigf(aZ[e]);
      float n  = tanh_fast(fmaf(rg, aNH[e], aNI[e]));
      float hn = fmaf(zg, hD1[e] - n, n);
      hD1[e] = hn;
      unsigned int pk = packsplit(hn);
      int idx = (lg * 4 + e) * HSTR + j;
      h1h[cb][idx] = (unsigned short)(pk >> 16);
      h1o[cb][idx] = (unsigned short)(pk & 0xFFFFu);
    }
    // no end-of-t barrier: next t's mid-barrier orders all remaining hazards
    xc0 = xn0; xc1 = xn1;
    pb = cb;
  }

  #pragma unroll
  for (int e = 0; e < 4; e++) {
    int sl = lg * 4 + e;
    zpk0[(size_t)(s0 + sl) * 64 + j] = packsplit(hD0[e]);
    zpk1[(size_t)(s0 + sl) * 64 + j] = packsplit(hD1[e]);
  }
}

// ===========================================================================
// FALLBACK (small ws): round-2 LDS-weight GRU, writes PACKED z
// ===========================================================================
__global__ void prep_kernel(const float* __restrict__ w_ih0, const float* __restrict__ w_hh0,
                            const float* __restrict__ w_ih1, const float* __restrict__ w_hh1,
                            float* __restrict__ wp)
{
  for (int i = blockIdx.x * blockDim.x + threadIdx.x; i < WP_TOTAL; i += gridDim.x * blockDim.x) {
    const float* src;
    int K, rel;
    if (i < WP_HH0)      { src = w_ih0; K = 32; rel = i; }
    else if (i < WP_IH1) { src = w_hh0; K = 64; rel = i - WP_HH0; }
    else if (i < WP_HH1) { src = w_ih1; K = 64; rel = i - WP_IH1; }
    else                 { src = w_hh1; K = 64; rel = i - WP_HH1; }
    int kr = rel & 3;
    int jj = (rel >> 2) & 63;
    int rest = rel >> 8;
    int g = rest % 3;
    int k4 = rest / 3;
    wp[i] = src[(g * 64 + jj) * K + k4 * 4 + kr];
  }
}

__global__ __launch_bounds__(256, 1) void gru_fallback(
    const float* __restrict__ x, const float* __restrict__ wpack,
    const float* __restrict__ b_ih0, const float* __restrict__ b_hh0,
    const float* __restrict__ b_ih1, const float* __restrict__ b_hh1,
    unsigned int* __restrict__ zout)
{
  __shared__ float wlds[36864];
  __shared__ float h0s[16][64];
  __shared__ float h1s[16][64];
  const int tid = threadIdx.x;
  {
    const float4* src = (const float4*)(wpack + WP_HH0);
    float4* dst = (float4*)wlds;
    #pragma unroll 4
    for (int i = tid; i < 9216; i += 256) dst[i] = src[i];
  }
  const int j  = tid & 63;
  const int sg = __builtin_amdgcn_readfirstlane(tid >> 6);
  const float br0  = b_ih0[j]      + b_hh0[j];
  const float bz0  = b_ih0[64 + j] + b_hh0[64 + j];
  const float bni0 = b_ih0[128 + j];
  const float bnh0 = b_hh0[128 + j];
  const float br1  = b_ih1[j]      + b_hh1[j];
  const float bz1  = b_ih1[64 + j] + b_hh1[64 + j];
  const float bni1 = b_ih1[128 + j];
  const float bnh1 = b_hh1[128 + j];
  const int s0 = blockIdx.x * 16;
  float h0r[4] = {0.f, 0.f, 0.f, 0.f};
  float h1r[4] = {0.f, 0.f, 0.f, 0.f};
  #pragma unroll
  for (int ss = 0; ss < 4; ss++) { h0s[sg * 4 + ss][j] = 0.f; h1s[sg * 4 + ss][j] = 0.f; }
  __syncthreads();
  const float4* wih0g = (const float4*)(wpack + WP_IH0);
  const float4* whh0l = (const float4*)(wlds);
  const float4* wih1l = (const float4*)(wlds + 12288);
  const float4* whh1l = (const float4*)(wlds + 24576);
  for (int t = 0; t < SEQ; t++) {
    float ar[4], az[4], ani[4], anh[4];
    #pragma unroll
    for (int ss = 0; ss < 4; ss++) { ar[ss] = br0; az[ss] = bz0; ani[ss] = bni0; anh[ss] = bnh0; }
    const float4* xr0 = (const float4*)(x + ((size_t)t * NBATCH + (s0 + sg * 4 + 0)) * FEAT);
    const float4* xr1 = (const float4*)(x + ((size_t)t * NBATCH + (s0 + sg * 4 + 1)) * FEAT);
    const float4* xr2 = (const float4*)(x + ((size_t)t * NBATCH + (s0 + sg * 4 + 2)) * FEAT);
    const float4* xr3 = (const float4*)(x + ((size_t)t * NBATCH + (s0 + sg * 4 + 3)) * FEAT);
    #pragma unroll
    for (int k4 = 0; k4 < 8; k4++) {
      float4 wr = wih0g[(k4 * 3 + 0) * 64 + j];
      float4 wz = wih0g[(k4 * 3 + 1) * 64 + j];
      float4 wn = wih0g[(k4 * 3 + 2) * 64 + j];
      float4 xv[4] = {xr0[k4], xr1[k4], xr2[k4], xr3[k4]};
      #pragma unroll
      for (int ss = 0; ss < 4; ss++) {
        DOT4(ar[ss],  wr, xv[ss]);
        DOT4(az[ss],  wz, xv[ss]);
        DOT4(ani[ss], wn, xv[ss]);
      }
    }
    #pragma unroll
    for (int k4 = 0; k4 < 16; k4++) {
      float4 wr = whh0l[(k4 * 3 + 0) * 64 + j];
      float4 wz = whh0l[(k4 * 3 + 1) * 64 + j];
      float4 wn = whh0l[(k4 * 3 + 2) * 64 + j];
      #pragma unroll
      for (int ss = 0; ss < 4; ss++) {
        float4 hv = *(const float4*)&h0s[sg * 4 + ss][k4 * 4];
        DOT4(ar[ss],  wr, hv);
        DOT4(az[ss],  wz, hv);
        DOT4(anh[ss], wn, hv);
      }
    }
    float h0n[4];
    #pragma unroll
    for (int ss = 0; ss < 4; ss++) {
      float rg = sigf(ar[ss]);
      float zg = sigf(az[ss]);
      float ng = tanh_fast(fmaf(rg, anh[ss], ani[ss]));
      h0n[ss] = fmaf(zg, h0r[ss] - ng, ng);
    }
    __syncthreads();
    #pragma unroll
    for (int ss = 0; ss < 4; ss++) { h0s[sg * 4 + ss][j] = h0n[ss]; h0r[ss] = h0n[ss]; }
    __syncthreads();
    #pragma unroll
    for (int ss = 0; ss < 4; ss++) { ar[ss] = br1; az[ss] = bz1; ani[ss] = bni1; anh[ss] = bnh1; }
    #pragma unroll
    for (int k4 = 0; k4 < 16; k4++) {
      float4 wr = wih1l[(k4 * 3 + 0) * 64 + j];
      float4 wz = wih1l[(k4 * 3 + 1) * 64 + j];
      float4 wn = wih1l[(k4 * 3 + 2) * 64 + j];
      #pragma unroll
      for (int ss = 0; ss < 4; ss++) {
        float4 hv = *(const float4*)&h0s[sg * 4 + ss][k4 * 4];
        DOT4(ar[ss],  wr, hv);
        DOT4(az[ss],  wz, hv);
        DOT4(ani[ss], wn, hv);
      }
    }
    #pragma unroll
    for (int k4 = 0; k4 < 16; k4++) {
      float4 wr = whh1l[(k4 * 3 + 0) * 64 + j];
      float4 wz = whh1l[(k4 * 3 + 1) * 64 + j];
      float4 wn = whh1l[(k4 * 3 + 2) * 64 + j];
      #pragma unroll
      for (int ss = 0; ss < 4; ss++) {
        float4 hv = *(const float4*)&h1s[sg * 4 + ss][k4 * 4];
        DOT4(ar[ss],  wr, hv);
        DOT4(az[ss],  wz, hv);
        DOT4(anh[ss], wn, hv);
      }
    }
    float h1n[4];
    #pragma unroll
    for (int ss = 0; ss < 4; ss++) {
      float rg = sigf(ar[ss]);
      float zg = sigf(az[ss]);
      float ng = tanh_fast(fmaf(rg, anh[ss], ani[ss]));
      h1n[ss] = fmaf(zg, h1r[ss] - ng, ng);
    }
    __syncthreads();
    #pragma unroll
    for (int ss = 0; ss < 4; ss++) { h1s[sg * 4 + ss][j] = h1n[ss]; h1r[ss] = h1n[ss]; }
    __syncthreads();
  }
  #pragma unroll
  for (int ss = 0; ss < 4; ss++) {
    int s = s0 + sg * 4 + ss;
    zout[(size_t)s * 64 + j]            = packsplit(h0r[ss]);
    zout[(size_t)(NBATCH + s) * 64 + j] = packsplit(h1r[ss]);
  }
}

// ===========================================================================
// MFMA GAT v5: KV-split flash attention, fixed-max softmax, V-prefetch.
//  - NSPLIT=2: grid 1024 = exactly 4 blk/CU x 256 CU -> ONE scheduling round
//  - V(mt+1) prefetched into 16 regs during mt compute; stage phase between
//    barriers is pure reg->LDS write (no global latency in critical section)
// ===========================================================================
__global__ __launch_bounds__(256, 4) void gat_mfma4(
    const unsigned int* __restrict__ zpk, const unsigned int* __restrict__ mbits,
    float* __restrict__ partO, float* __restrict__ partD,
    float* __restrict__ out, int nsplit)
{
  __shared__ unsigned int VT[64 * 68];   // packed hi|lo, [d][s] layout
  __shared__ float        PS[64 * 68];   // P fp32, wave-private rows
  const int tid = threadIdx.x;
  const int w = tid >> 6, l = tid & 63, lr = l & 15, lg = l >> 4;
  const int blk  = blockIdx.x;
  const int lbrt = blk / nsplit;
  const int half = blk - lbrt * nsplit;
  const int rt = lbrt & 15;
  const int lb = lbrt >> 4;
  const int tiles = 16 / nsplit;
  const int mt0 = half * tiles;
  const unsigned int* zb = zpk + (size_t)lb * 65536;
  const int n0 = rt * 64;

  bf16x8 Qh[2], Ql[2];
  #pragma unroll
  for (int ks = 0; ks < 2; ks++)
    unpack8(&zb[(size_t)(n0 + w * 16 + lr) * 64 + ks * 32 + lg * 8], Qh[ks], Ql[ks]);

  // preload V(mt0): thread covers V rows w*16..w*16+15, col d=l
  unsigned int vpre[16];
  #pragma unroll
  for (int r = 0; r < 16; r++)
    vpre[r] = zb[(size_t)(mt0 * 64 + w * 16 + r) * 64 + l];

  f32x4 O[4];
  float D[4] = {0.f, 0.f, 0.f, 0.f};
  #pragma unroll
  for (int ct = 0; ct < 4; ct++)
    #pragma unroll
    for (int e = 0; e < 4; e++) O[ct][e] = 0.f;

  #pragma unroll 1
  for (int mt = mt0; mt < mt0 + tiles; ++mt) {
    __syncthreads();   // prev iteration's VT reads complete
    // stage VT from prefetched regs (transposed [d=l][s=w*16+r])
    #pragma unroll
    for (int q = 0; q < 4; q++)
      *(uint4*)&VT[l * 68 + w * 16 + q * 4] =
          make_uint4(vpre[q * 4], vpre[q * 4 + 1], vpre[q * 4 + 2], vpre[q * 4 + 3]);
    // issue prefetch for next tile (redundant wrap at last iter)
    {
      const int nt = (mt + 1 < mt0 + tiles) ? (mt + 1) : mt0;
      #pragma unroll
      for (int r = 0; r < 16; r++)
        vpre[r] = zb[(size_t)(nt * 64 + w * 16 + r) * 64 + l];
    }
    __syncthreads();   // VT ready

    // S = Q.K^T (3-term split, full precision through exp)
    f32x4 S[4];
    #pragma unroll
    for (int ct = 0; ct < 4; ct++)
      #pragma unroll
      for (int e = 0; e < 4; e++) S[ct][e] = 0.f;
    #pragma unroll
    for (int ks = 0; ks < 2; ks++) {
      #pragma unroll
      for (int ct = 0; ct < 4; ct++) {
        bf16x8 Kh, Kl;
        unpack8(&zb[(size_t)(mt * 64 + ct * 16 + lr) * 64 + ks * 32 + lg * 8], Kh, Kl);
        S[ct] = MFMA_B16(Qh[ks], Kh, S[ct]);
        S[ct] = MFMA_B16(Ql[ks], Kh, S[ct]);
        S[ct] = MFMA_B16(Qh[ks], Kl, S[ct]);
      }
    }

    // fixed-max masked softmax: P = exp(leaky(S)-64), masked/zero -> 0
    #pragma unroll
    for (int e = 0; e < 4; e++) {
      const int row = n0 + w * 16 + lg * 4 + e;
      const uint2 mw = *(const uint2*)&mbits[(size_t)row * 32 + mt * 2];
      const unsigned int sel[4] = {mw.x >> lr, mw.x >> (16 + lr), mw.y >> lr, mw.y >> (16 + lr)};
      float ds = 0.f;
      #pragma unroll
      for (int ct = 0; ct < 4; ct++) {
        float v = S[ct][e];
        float lrv = v > 0.f ? v : 0.1f * v;
        float p = ((sel[ct] & 1u) && lrv != 0.0f) ? __expf(lrv - 64.0f) : 0.0f;
        ds += p;
        PS[(w * 16 + lg * 4 + e) * 68 + ct * 16 + lr] = p;
      }
      D[e] += ds;
    }

    // O += P.V  (P bf16-RNE single term; V full hi+lo)
    #pragma unroll
    for (int ks = 0; ks < 2; ks++) {
      const float* pp = &PS[(w * 16 + lr) * 68 + ks * 32 + lg * 8];
      float4 p0 = *(const float4*)pp;
      float4 p1 = *(const float4*)(pp + 4);
      float fa[8] = {p0.x, p0.y, p0.z, p0.w, p1.x, p1.y, p1.z, p1.w};
      B8u H;
      #pragma unroll
      for (int i = 0; i < 8; i++)
        H.s[i] = (unsigned short)((__float_as_uint(fa[i]) + 0x8000u) >> 16);
      bf16x8 Ph = H.v;
      #pragma unroll
      for (int ct = 0; ct < 4; ct++) {
        bf16x8 Vh, Vl;
        unpack8(&VT[(ct * 16 + lr) * 68 + ks * 32 + lg * 8], Vh, Vl);
        O[ct] = MFMA_B16(Ph, Vh, O[ct]);
        O[ct] = MFMA_B16(Ph, Vl, O[ct]);
      }
    }
  }

  // reduce D across the 16 lanes of each row group (once, not per-mt)
  #pragma unroll
  for (int e = 0; e < 4; e++) {
    #pragma unroll
    for (int sw = 1; sw < 16; sw <<= 1) D[e] += __shfl_xor(D[e], sw, 16);
  }

  if (nsplit == 1) {
    #pragma unroll
    for (int e = 0; e < 4; e++) {
      float inv = 1.0f / D[e];
      size_t rowo = ((size_t)lb * 1024 + n0 + w * 16 + lg * 4 + e) * 64;
      #pragma unroll
      for (int ct = 0; ct < 4; ct++)
        out[rowo + ct * 16 + lr] = O[ct][e] * inv;
    }
  } else {
    float* po = partO + (size_t)blk * 4096;
    #pragma unroll
    for (int e = 0; e < 4; e++) {
      int row = w * 16 + lg * 4 + e;
      #pragma unroll
      for (int ct = 0; ct < 4; ct++)
        po[row * 64 + ct * 16 + lr] = O[ct][e];
      if (lr == 0) partD[(size_t)blk * 64 + row] = D[e];
    }
  }
}

// merge: out = sum_i O_i / sum_i D_i  (fixed max -> plain sums, no exp)
__global__ __launch_bounds__(256) void gat_combine(
    const float* __restrict__ partO, const float* __restrict__ partD,
    float* __restrict__ out, int nsplit)
{
  const int lbrt = blockIdx.x;             // 0..511
  const int q  = threadIdx.x >> 2;         // 0..63
  const int dc = (threadIdx.x & 3) * 16;   // 0,16,32,48
  float dt = 0.f;
  for (int i = 0; i < nsplit; i++) dt += partD[(size_t)(lbrt * nsplit + i) * 64 + q];
  float inv = 1.0f / dt;
  float* op = out + ((size_t)lbrt * 64 + q) * 64 + dc;
  #pragma unroll
  for (int v = 0; v < 4; v++) {
    float4 acc = make_float4(0.f, 0.f, 0.f, 0.f);
    for (int i = 0; i < nsplit; i++) {
      const float4 o = *(const float4*)(partO + (size_t)(lbrt * nsplit + i) * 4096 + q * 64 + dc + v * 4);
      acc.x += o.x; acc.y += o.y; acc.z += o.z; acc.w += o.w;
    }
    *(float4*)(op + v * 4) = make_float4(acc.x * inv, acc.y * inv, acc.z * inv, acc.w * inv);
  }
}

extern "C" void kernel_launch(void* const* d_in, const int* in_sizes, int n_in,
                              void* d_out, int out_size, void* d_ws, size_t ws_size,
                              hipStream_t stream) {
  const float* h     = (const float*)d_in[0];
  const int*   mask  = (const int*)d_in[1];
  const float* w_ih0 = (const float*)d_in[2];
  const float* w_hh0 = (const float*)d_in[3];
  const float* b_ih0 = (const float*)d_in[4];
  const float* b_hh0 = (const float*)d_in[5];
  const float* w_ih1 = (const float*)d_in[6];
  const float* w_hh1 = (const float*)d_in[7];
  const float* b_ih1 = (const float*)d_in[8];
  const float* b_hh1 = (const float*)d_in[9];
  float* out = (float*)d_out;

  char* wsb = (char*)d_ws;
  unsigned int* zpk = (unsigned int*)wsb;                     // [2][16384][64] packed u32
  const size_t Z_BYTES  = (size_t)2 * NBATCH * 64 * 4;        // 8388608
  const size_t PART_OFF = Z_BYTES + 176128;                   // past 172KB frag weights
  const size_t PO_BYTES = (size_t)512 * NSPLIT * 4096 * 4;    // 16.8MB
  const size_t PD_BYTES = (size_t)512 * NSPLIT * 64 * 4;      // 256KB
  const size_t MB_OFF   = PART_OFF + PO_BYTES + PD_BYTES;
  const size_t NEED_FAST = MB_OFF + 131072;

  if (ws_size >= NEED_FAST) {
    unsigned short* wfrag = (unsigned short*)(wsb + Z_BYTES);
    float* partO  = (float*)(wsb + PART_OFF);
    float* partD  = (float*)(wsb + PART_OFF + PO_BYTES);
    unsigned int* mbits = (unsigned int*)(wsb + MB_OFF);
    prep_frag_kernel<<<168, 256, 0, stream>>>(w_ih0, w_hh0, w_ih1, w_hh1, wfrag);
    mask_pack<<<128, 256, 0, stream>>>(mask, mbits);
    gru_fused<<<1024, 256, 0, stream>>>(h, wfrag, b_ih0, b_hh0, b_ih1, b_hh1,
                                        zpk, zpk + (size_t)NBATCH * 64);
    gat_mfma4<<<512 * NSPLIT, 256, 0, stream>>>(zpk, mbits, partO, partD, out, NSPLIT);
    gat_combine<<<512, 256, 0, stream>>>(partO, partD, out, NSPLIT);
  } else {
    float* wpack = (float*)(wsb + Z_BYTES);
    unsigned int* mbits = (unsigned int*)(wsb + Z_BYTES + 172032);
    prep_kernel<<<24, 256, 0, stream>>>(w_ih0, w_hh0, w_ih1, w_hh1, wpack);
    mask_pack<<<128, 256, 0, stream>>>(mask, mbits);
    gru_fallback<<<1024, 256, 0, stream>>>(h, wpack, b_ih0, b_hh0, b_ih1, b_hh1, zpk);
    gat_mfma4<<<512, 256, 0, stream>>>(zpk, mbits, nullptr, nullptr, out, 1);
  }
}